// Round 1
// baseline (753.197 us; speedup 1.0000x reference)
//
#include <hip/hip_runtime.h>
#include <hip/hip_bf16.h>

typedef unsigned short u16;
typedef unsigned int u32;

#define WIDTH 64
#define KERW 4096   // 64*64
#define K2DIM 128
#define DEPTH 4

__device__ __forceinline__ u16 f2bf(float f) {
    union { float f; u32 u; } v; v.f = f;
    u32 r = v.u + 0x7FFFu + ((v.u >> 16) & 1u);
    return (u16)(r >> 16);
}
__device__ __forceinline__ float bflo(u32 u) { return __uint_as_float(u << 16); }
__device__ __forceinline__ float bfhi(u32 u) { return __uint_as_float(u & 0xFFFF0000u); }

// ---------------- fc1: x0[n][j] = fc1_w[j]*x[n] + fc1_b[j] ----------------
__global__ void fc1_k(const float* __restrict__ x, const float* __restrict__ w,
                      const float* __restrict__ b, float* __restrict__ x0, int N) {
    int idx = blockIdx.x * 256 + threadIdx.x;
    if (idx < N * WIDTH) {
        int n = idx >> 6, j = idx & 63;
        x0[idx] = w[j] * x[n] + b[j];
    }
}

// ---------------- edge counts (scatter-mean denominators) ----------------
__global__ void count_k(const int* __restrict__ dst1, int E,
                        const int* __restrict__ dst2, int Eb,
                        float* __restrict__ cnt, int N) {
    int i = blockIdx.x * 256 + threadIdx.x;
    if (i < E) atomicAdd(&cnt[dst1[i]], 1.0f);
    else if (i < E + Eb) atomicAdd(&cnt[N + dst2[i - E]], 1.0f);
}

// ---------------- kernel-MLP layers 1+2: edge_attr[E,6] -> h2[E,128] ----------------
__global__ __launch_bounds__(128) void mlp12_k(const float* __restrict__ ea,
                                               const float* __restrict__ w1, const float* __restrict__ b1,
                                               const float* __restrict__ w2, const float* __restrict__ b2,
                                               float* __restrict__ h2, int E) {
    __shared__ float sea[8];
    __shared__ float sh1[64];
    int e = blockIdx.x, t = threadIdx.x;
    if (t < 6) sea[t] = ea[(size_t)e * 6 + t];
    __syncthreads();
    if (t < 64) {
        float a = b1[t];
        #pragma unroll
        for (int k = 0; k < 6; ++k) a += sea[k] * w1[t * 6 + k];
        sh1[t] = fmaxf(a, 0.f);
    }
    __syncthreads();
    float a = b2[t];
    #pragma unroll 8
    for (int j = 0; j < 64; ++j) a += sh1[j] * w2[t * 64 + j];
    h2[(size_t)e * K2DIM + t] = fmaxf(a, 0.f);
}

// ---------------- big GEMM: Wt[e][c] = h2[e] . w3[pr(c)] + b3[pr(c)], bf16 out ----------------
// c = o*64+i ; pr(c) = i*64+o  (store transposed so msg kernel reads [e][o][i] contiguous in i)
__global__ __launch_bounds__(256) void w3_gemm_k(const float* __restrict__ h2,
                                                 const float* __restrict__ w3,
                                                 const float* __restrict__ b3,
                                                 u16* __restrict__ Wt, int E) {
    __shared__ float As[128][64];
    __shared__ float Bs[128][64];
    int eb = blockIdx.x * 64;
    int cb = blockIdx.y * 64;
    int t = threadIdx.x;
    {
        int er = t & 63, kc = t >> 6;
        int eg = eb + er; if (eg >= E) eg = E - 1;
        const float4* asrc = (const float4*)(h2 + (size_t)eg * 128);
        int c = cb + er;
        int pr = ((c & 63) << 6) | (c >> 6);
        const float4* bsrc = (const float4*)(w3 + (size_t)pr * 128);
        #pragma unroll
        for (int jj = 0; jj < 8; ++jj) {
            int k4 = kc * 8 + jj;
            float4 va = asrc[k4];
            As[k4 * 4 + 0][er] = va.x; As[k4 * 4 + 1][er] = va.y;
            As[k4 * 4 + 2][er] = va.z; As[k4 * 4 + 3][er] = va.w;
            float4 vb = bsrc[k4];
            Bs[k4 * 4 + 0][er] = vb.x; Bs[k4 * 4 + 1][er] = vb.y;
            Bs[k4 * 4 + 2][er] = vb.z; Bs[k4 * 4 + 3][er] = vb.w;
        }
    }
    __syncthreads();
    int tx = t & 15, ty = t >> 4;
    float acc[4][4] = {};
    #pragma unroll 8
    for (int k = 0; k < 128; ++k) {
        float4 a = *(const float4*)&As[k][ty * 4];
        float4 b = *(const float4*)&Bs[k][tx * 4];
        acc[0][0] += a.x * b.x; acc[0][1] += a.x * b.y; acc[0][2] += a.x * b.z; acc[0][3] += a.x * b.w;
        acc[1][0] += a.y * b.x; acc[1][1] += a.y * b.y; acc[1][2] += a.y * b.z; acc[1][3] += a.y * b.w;
        acc[2][0] += a.z * b.x; acc[2][1] += a.z * b.y; acc[2][2] += a.z * b.z; acc[2][3] += a.z * b.w;
        acc[3][0] += a.w * b.x; acc[3][1] += a.w * b.y; acc[3][2] += a.w * b.z; acc[3][3] += a.w * b.w;
    }
    #pragma unroll
    for (int i = 0; i < 4; ++i) {
        int eg = eb + ty * 4 + i;
        if (eg >= E) continue;
        ushort4 pk;
        {
            int c0 = cb + tx * 4;
            int p0 = ((c0 & 63) << 6) | (c0 >> 6);
            int p1 = (((c0 + 1) & 63) << 6) | ((c0 + 1) >> 6);
            int p2 = (((c0 + 2) & 63) << 6) | ((c0 + 2) >> 6);
            int p3 = (((c0 + 3) & 63) << 6) | ((c0 + 3) >> 6);
            pk.x = f2bf(acc[i][0] + b3[p0]);
            pk.y = f2bf(acc[i][1] + b3[p1]);
            pk.z = f2bf(acc[i][2] + b3[p2]);
            pk.w = f2bf(acc[i][3] + b3[p3]);
        }
        *(ushort4*)(Wt + (size_t)eg * KERW + cb + tx * 4) = pk;
    }
}

// ---------------- message + scatter-add: wave per edge ----------------
// Wt layout [e][o*64+i]: lane o reads 64 contiguous bf16 (its W column)
__global__ __launch_bounds__(256) void msg_k(const float* __restrict__ h,
                                             const u16* __restrict__ Wt,
                                             const int* __restrict__ src, const int* __restrict__ dst,
                                             float* __restrict__ s, int E) {
    __shared__ float hs[4][64];
    int w = threadIdx.x >> 6, o = threadIdx.x & 63;
    int e = blockIdx.x * 4 + w;
    bool valid = e < E;
    int ec = valid ? e : 0;
    int sv = src[ec];
    hs[w][o] = h[(size_t)sv * 64 + o];
    __syncthreads();
    const u16* wr = Wt + (size_t)ec * KERW + o * 64;
    float acc = 0.f;
    #pragma unroll
    for (int jj = 0; jj < 8; ++jj) {
        uint4 v = *(const uint4*)(wr + jj * 8);
        const float* hh = &hs[w][jj * 8];
        acc += bflo(v.x) * hh[0]; acc += bfhi(v.x) * hh[1];
        acc += bflo(v.y) * hh[2]; acc += bfhi(v.y) * hh[3];
        acc += bflo(v.z) * hh[4]; acc += bfhi(v.z) * hh[5];
        acc += bflo(v.w) * hh[6]; acc += bfhi(v.w) * hh[7];
    }
    if (valid) atomicAdd(&s[(size_t)dst[ec] * 64 + o], acc);
}

// ---------------- combine: mean + h@(root1+root2) + biases, relu, +x0 ----------------
__global__ __launch_bounds__(256) void combine_k(const float* __restrict__ h,
                                                 const float* __restrict__ s,   // [2][N][64]
                                                 const float* __restrict__ cnt, // [2][N]
                                                 const float* __restrict__ root1, const float* __restrict__ root2,
                                                 const float* __restrict__ bias1, const float* __restrict__ bias2,
                                                 const float* __restrict__ x0, float* __restrict__ hout, int N) {
    __shared__ float rs[64][64];
    __shared__ float hr[4][64];
    int t = threadIdx.x;
    for (int j = t; j < 4096; j += 256) rs[j >> 6][j & 63] = root1[j] + root2[j];
    int w = t >> 6, o = t & 63;
    int n = blockIdx.x * 4 + w;
    bool valid = n < N;
    int nc = valid ? n : 0;
    hr[w][o] = h[(size_t)nc * 64 + o];
    __syncthreads();
    float inv1 = 1.0f / fmaxf(cnt[nc], 1.0f);
    float inv2 = 1.0f / fmaxf(cnt[N + nc], 1.0f);
    float acc = s[(size_t)nc * 64 + o] * inv1
              + s[(size_t)(N + nc) * 64 + o] * inv2
              + bias1[o] + bias2[o];
    #pragma unroll 8
    for (int i = 0; i < 64; ++i) acc += hr[w][i] * rs[i][o];
    if (valid) hout[(size_t)n * 64 + o] = fmaxf(acc, 0.f) + x0[(size_t)n * 64 + o];
}

// ---------------- head: out[n] = fc3( relu(fc2(h[n])) ) ----------------
__global__ __launch_bounds__(128) void head_k(const float* __restrict__ h,
                                              const float* __restrict__ fc2w, const float* __restrict__ fc2b,
                                              const float* __restrict__ fc3w, const float* __restrict__ fc3b,
                                              float* __restrict__ out, int N) {
    __shared__ float hr[64];
    __shared__ float red[128];
    int n = blockIdx.x, t = threadIdx.x;
    if (t < 64) hr[t] = h[(size_t)n * 64 + t];
    __syncthreads();
    float a = fc2b[t];
    #pragma unroll 8
    for (int i = 0; i < 64; ++i) a += hr[i] * fc2w[t * 64 + i];
    red[t] = fmaxf(a, 0.f) * fc3w[t];
    __syncthreads();
    if (t < 64) {
        float v = red[t] + red[t + 64];
        for (int off = 32; off; off >>= 1) v += __shfl_down(v, off);
        if (t == 0) out[n] = v + fc3b[0];
    }
}

extern "C" void kernel_launch(void* const* d_in, const int* in_sizes, int n_in,
                              void* d_out, int out_size, void* d_ws, size_t ws_size,
                              hipStream_t stream) {
    const float* x    = (const float*)d_in[0];
    const int*   ei   = (const int*)d_in[1];
    const float* ea   = (const float*)d_in[2];
    const int*   eib  = (const int*)d_in[3];
    const float* eab  = (const float*)d_in[4];
    const float* fc1w = (const float*)d_in[5];
    const float* fc1b = (const float*)d_in[6];
    const float* fc2w = (const float*)d_in[7];
    const float* fc2b = (const float*)d_in[8];
    const float* fc3w = (const float*)d_in[9];
    const float* fc3b = (const float*)d_in[10];
    const float* k1w1 = (const float*)d_in[11];
    const float* k1b1 = (const float*)d_in[12];
    const float* k1w2 = (const float*)d_in[13];
    const float* k1b2 = (const float*)d_in[14];
    const float* k1w3 = (const float*)d_in[15];
    const float* k1b3 = (const float*)d_in[16];
    const float* root1 = (const float*)d_in[17];
    const float* bias1 = (const float*)d_in[18];
    const float* k2w1 = (const float*)d_in[19];
    const float* k2b1 = (const float*)d_in[20];
    const float* k2w2 = (const float*)d_in[21];
    const float* k2b2 = (const float*)d_in[22];
    const float* k2w3 = (const float*)d_in[23];
    const float* k2b3 = (const float*)d_in[24];
    const float* root2 = (const float*)d_in[25];
    const float* bias2 = (const float*)d_in[26];
    float* out = (float*)d_out;

    const int N  = in_sizes[0];
    const int E  = in_sizes[2] / 6;
    const int Eb = in_sizes[4] / 6;

    // ---- workspace carve (256B aligned) ----
    char* p = (char*)d_ws;
    auto alloc = [&](size_t bytes) {
        char* r = p;
        p += (bytes + 255) & ~(size_t)255;
        return (void*)r;
    };
    float* x0   = (float*)alloc((size_t)N * 64 * 4);
    float* hA   = (float*)alloc((size_t)N * 64 * 4);
    float* hB   = (float*)alloc((size_t)N * 64 * 4);
    float* sbuf = (float*)alloc((size_t)2 * N * 64 * 4);   // s1 | s2
    float* cnt  = (float*)alloc((size_t)2 * N * 4);        // cnt1 | cnt2
    float* h2a  = (float*)alloc((size_t)E * K2DIM * 4);
    float* h2b  = (float*)alloc((size_t)Eb * K2DIM * 4);
    u16*   W1   = (u16*)alloc((size_t)E * KERW * 2);
    u16*   W2   = (u16*)alloc((size_t)Eb * KERW * 2);
    (void)ws_size;

    const int* src1 = ei;       const int* dst1 = ei + E;
    const int* src2 = eib;      const int* dst2 = eib + Eb;

    // ---- precompute phase ----
    hipMemsetAsync(cnt, 0, (size_t)2 * N * 4, stream);
    {
        int tot = E + Eb;
        count_k<<<(tot + 255) / 256, 256, 0, stream>>>(dst1, E, dst2, Eb, cnt, N);
    }
    fc1_k<<<((size_t)N * 64 + 255) / 256, 256, 0, stream>>>(x, fc1w, fc1b, x0, N);

    mlp12_k<<<E, 128, 0, stream>>>(ea, k1w1, k1b1, k1w2, k1b2, h2a, E);
    mlp12_k<<<Eb, 128, 0, stream>>>(eab, k2w1, k2b1, k2w2, k2b2, h2b, Eb);

    {
        dim3 g1((E + 63) / 64, 64);
        w3_gemm_k<<<g1, 256, 0, stream>>>(h2a, k1w3, k1b3, W1, E);
        dim3 g2((Eb + 63) / 64, 64);
        w3_gemm_k<<<g2, 256, 0, stream>>>(h2b, k2w3, k2b3, W2, Eb);
    }

    // ---- 4 message-passing layers ----
    const float* hcur = x0;
    float* bufs[2] = { hA, hB };
    for (int l = 0; l < DEPTH; ++l) {
        float* hnext = bufs[l & 1];
        hipMemsetAsync(sbuf, 0, (size_t)2 * N * 64 * 4, stream);
        msg_k<<<(E + 3) / 4, 256, 0, stream>>>(hcur, W1, src1, dst1, sbuf, E);
        msg_k<<<(Eb + 3) / 4, 256, 0, stream>>>(hcur, W2, src2, dst2, sbuf + (size_t)N * 64, Eb);
        combine_k<<<(N + 3) / 4, 256, 0, stream>>>(hcur, sbuf, cnt, root1, root2, bias1, bias2,
                                                   x0, hnext, N);
        hcur = hnext;
    }

    // ---- head ----
    head_k<<<N, 128, 0, stream>>>(hcur, fc2w, fc2b, fc3w, fc3b, out, N);
}

// Round 2
// 476.023 us; speedup vs baseline: 1.5823x; 1.5823x over previous
//
#include <hip/hip_runtime.h>
#include <hip/hip_bf16.h>

typedef unsigned short u16;
typedef unsigned int u32;

#define WIDTH 64
#define KERW 4096   // 64*64
#define K2DIM 128
#define DEPTH 4

typedef __attribute__((ext_vector_type(8))) short short8;
typedef __attribute__((ext_vector_type(4))) float f32x4;

__device__ __forceinline__ u16 f2bf(float f) {
    union { float f; u32 u; } v; v.f = f;
    u32 r = v.u + 0x7FFFu + ((v.u >> 16) & 1u);
    return (u16)(r >> 16);
}
__device__ __forceinline__ float bflo(u32 u) { return __uint_as_float(u << 16); }
__device__ __forceinline__ float bfhi(u32 u) { return __uint_as_float(u & 0xFFFF0000u); }

// ---------------- fc1: x0[n][j] = fc1_w[j]*x[n] + fc1_b[j] ----------------
__global__ void fc1_k(const float* __restrict__ x, const float* __restrict__ w,
                      const float* __restrict__ b, float* __restrict__ x0, int N) {
    int idx = blockIdx.x * 256 + threadIdx.x;
    if (idx < N * WIDTH) {
        int n = idx >> 6, j = idx & 63;
        x0[idx] = w[j] * x[n] + b[j];
    }
}

// ---------------- edge counts (scatter-mean denominators) ----------------
__global__ void count_k(const int* __restrict__ dst1, int E,
                        const int* __restrict__ dst2, int Eb,
                        float* __restrict__ cnt, int N) {
    int i = blockIdx.x * 256 + threadIdx.x;
    if (i < E) atomicAdd(&cnt[dst1[i]], 1.0f);
    else if (i < E + Eb) atomicAdd(&cnt[N + dst2[i - E]], 1.0f);
}

// ---------------- kernel-MLP layers 1+2: edge_attr[E,6] -> h2[E,128] bf16 ----------------
__global__ __launch_bounds__(128) void mlp12_k(const float* __restrict__ ea,
                                               const float* __restrict__ w1, const float* __restrict__ b1,
                                               const float* __restrict__ w2, const float* __restrict__ b2,
                                               u16* __restrict__ h2, int E) {
    __shared__ float sea[8];
    __shared__ float sh1[64];
    int e = blockIdx.x, t = threadIdx.x;
    if (t < 6) sea[t] = ea[(size_t)e * 6 + t];
    __syncthreads();
    if (t < 64) {
        float a = b1[t];
        #pragma unroll
        for (int k = 0; k < 6; ++k) a += sea[k] * w1[t * 6 + k];
        sh1[t] = fmaxf(a, 0.f);
    }
    __syncthreads();
    float a = b2[t];
    #pragma unroll 8
    for (int j = 0; j < 64; ++j) a += sh1[j] * w2[t * 64 + j];
    h2[(size_t)e * K2DIM + t] = f2bf(fmaxf(a, 0.f));
}

// ---------------- prep B panel: Bp[c][k] = bf16(w3[pr(c)][k]), b3p[c] = b3[pr(c)] ----------------
// pr(c) = (c&63)*64 + (c>>6)   (c = o*64+i so msg kernel reads [e][o][i] contiguous in i)
__global__ void prep_b_k(const float* __restrict__ w3, const float* __restrict__ b3,
                         u16* __restrict__ Bp, float* __restrict__ b3p) {
    int idx = blockIdx.x * 256 + threadIdx.x;   // 4096*128
    int c = idx >> 7, k = idx & 127;
    int pr = ((c & 63) << 6) | (c >> 6);
    Bp[idx] = f2bf(w3[(size_t)pr * 128 + k]);
    if (k == 0) b3p[c] = b3[pr];
}

// ---------------- big GEMM via MFMA: Wt[e][c] = h2[e] . Bp[c] + b3p[c], bf16 out ----------------
// 128x128 tile, K=128 single-shot, 4 waves (2x2 of 64x64), 16x16x32 bf16 MFMA.
// LDS tiles XOR-swizzled: byte ^= (row&7)<<4 (row stride 256B would be 16-way conflict).
__global__ __launch_bounds__(256) void w3_mfma_k(const u16* __restrict__ h2,  // [E][128] bf16
                                                 const u16* __restrict__ Bp,  // [4096][128] bf16
                                                 const float* __restrict__ b3p,
                                                 u16* __restrict__ Wt, int E) {
    __shared__ u16 As[128 * 128];
    __shared__ u16 Bs[128 * 128];
    int eb = blockIdx.x * 128, cb = blockIdx.y * 128;
    int t = threadIdx.x;
    {
        int r = t & 127, p = t >> 7;           // 2 threads per row, 128B each
        int eg = eb + r; if (eg >= E) eg = E - 1;
        const uint4* srcA = (const uint4*)(h2 + (size_t)eg * 128 + p * 64);
        const uint4* srcB = (const uint4*)(Bp + (size_t)(cb + r) * 128 + p * 64);
        #pragma unroll
        for (int j = 0; j < 8; ++j) {
            int byteoff = r * 256 + p * 128 + j * 16;
            int sw = byteoff ^ ((r & 7) << 4);
            *(uint4*)((char*)As + sw) = srcA[j];
            *(uint4*)((char*)Bs + sw) = srcB[j];
        }
    }
    __syncthreads();
    int lane = t & 63, wv = t >> 6;
    int wr = (wv >> 1) * 64, wc = (wv & 1) * 64;
    int lr = lane & 15, lg = lane >> 4;
    f32x4 acc[4][4] = {};
    #pragma unroll
    for (int kk = 0; kk < 4; ++kk) {
        short8 af[4], bf[4];
        #pragma unroll
        for (int i = 0; i < 4; ++i) {
            int row = wr + i * 16 + lr;                        // A: row = lane&15
            int ao = (row * 256 + (kk * 32 + lg * 8) * 2);    // k = (lane>>4)*8 + j
            af[i] = *(const short8*)((const char*)As + (ao ^ ((row & 7) << 4)));
            int col = wc + i * 16 + lr;                        // B: col = lane&15
            int bo = (col * 256 + (kk * 32 + lg * 8) * 2);
            bf[i] = *(const short8*)((const char*)Bs + (bo ^ ((col & 7) << 4)));
        }
        #pragma unroll
        for (int m = 0; m < 4; ++m)
            #pragma unroll
            for (int n = 0; n < 4; ++n)
                acc[m][n] = __builtin_amdgcn_mfma_f32_16x16x32_bf16(af[m], bf[n], acc[m][n], 0, 0, 0);
    }
    // epilogue: D col = lane&15, row = (lane>>4)*4 + reg
    #pragma unroll
    for (int m = 0; m < 4; ++m) {
        #pragma unroll
        for (int n = 0; n < 4; ++n) {
            int c = cb + wc + n * 16 + lr;
            float bb = b3p[c];
            #pragma unroll
            for (int r4 = 0; r4 < 4; ++r4) {
                int eg = eb + wr + m * 16 + lg * 4 + r4;
                if (eg < E) Wt[(size_t)eg * KERW + c] = f2bf(acc[m][n][r4] + bb);
            }
        }
    }
}

// ---------------- message + scatter-add: wave per edge ----------------
// Wt layout [e][o*64+i]: lane o reads 64 contiguous bf16 (its W column)
__global__ __launch_bounds__(256) void msg_k(const float* __restrict__ h,
                                             const u16* __restrict__ Wt,
                                             const int* __restrict__ src, const int* __restrict__ dst,
                                             float* __restrict__ s, int E) {
    __shared__ float hs[4][64];
    int w = threadIdx.x >> 6, o = threadIdx.x & 63;
    int e = blockIdx.x * 4 + w;
    bool valid = e < E;
    int ec = valid ? e : 0;
    int sv = src[ec];
    hs[w][o] = h[(size_t)sv * 64 + o];
    __syncthreads();
    const u16* wr = Wt + (size_t)ec * KERW + o * 64;
    float acc = 0.f;
    #pragma unroll
    for (int jj = 0; jj < 8; ++jj) {
        uint4 v = *(const uint4*)(wr + jj * 8);
        const float* hh = &hs[w][jj * 8];
        acc += bflo(v.x) * hh[0]; acc += bfhi(v.x) * hh[1];
        acc += bflo(v.y) * hh[2]; acc += bfhi(v.y) * hh[3];
        acc += bflo(v.z) * hh[4]; acc += bfhi(v.z) * hh[5];
        acc += bflo(v.w) * hh[6]; acc += bfhi(v.w) * hh[7];
    }
    if (valid) atomicAdd(&s[(size_t)dst[ec] * 64 + o], acc);
}

// ---------------- combine: mean + h@(root1+root2) + biases, relu, +x0 ----------------
__global__ __launch_bounds__(256) void combine_k(const float* __restrict__ h,
                                                 const float* __restrict__ s,   // [2][N][64]
                                                 const float* __restrict__ cnt, // [2][N]
                                                 const float* __restrict__ root1, const float* __restrict__ root2,
                                                 const float* __restrict__ bias1, const float* __restrict__ bias2,
                                                 const float* __restrict__ x0, float* __restrict__ hout, int N) {
    __shared__ float rs[64][64];
    __shared__ float hr[4][64];
    int t = threadIdx.x;
    for (int j = t; j < 4096; j += 256) rs[j >> 6][j & 63] = root1[j] + root2[j];
    int w = t >> 6, o = t & 63;
    int n = blockIdx.x * 4 + w;
    bool valid = n < N;
    int nc = valid ? n : 0;
    hr[w][o] = h[(size_t)nc * 64 + o];
    __syncthreads();
    float inv1 = 1.0f / fmaxf(cnt[nc], 1.0f);
    float inv2 = 1.0f / fmaxf(cnt[N + nc], 1.0f);
    float acc = s[(size_t)nc * 64 + o] * inv1
              + s[(size_t)(N + nc) * 64 + o] * inv2
              + bias1[o] + bias2[o];
    #pragma unroll 8
    for (int i = 0; i < 64; ++i) acc += hr[w][i] * rs[i][o];
    if (valid) hout[(size_t)n * 64 + o] = fmaxf(acc, 0.f) + x0[(size_t)n * 64 + o];
}

// ---------------- head: out[n] = fc3( relu(fc2(h[n])) ) ----------------
__global__ __launch_bounds__(128) void head_k(const float* __restrict__ h,
                                              const float* __restrict__ fc2w, const float* __restrict__ fc2b,
                                              const float* __restrict__ fc3w, const float* __restrict__ fc3b,
                                              float* __restrict__ out, int N) {
    __shared__ float hr[64];
    __shared__ float red[128];
    int n = blockIdx.x, t = threadIdx.x;
    if (t < 64) hr[t] = h[(size_t)n * 64 + t];
    __syncthreads();
    float a = fc2b[t];
    #pragma unroll 8
    for (int i = 0; i < 64; ++i) a += hr[i] * fc2w[t * 64 + i];
    red[t] = fmaxf(a, 0.f) * fc3w[t];
    __syncthreads();
    if (t < 64) {
        float v = red[t] + red[t + 64];
        for (int off = 32; off; off >>= 1) v += __shfl_down(v, off);
        if (t == 0) out[n] = v + fc3b[0];
    }
}

extern "C" void kernel_launch(void* const* d_in, const int* in_sizes, int n_in,
                              void* d_out, int out_size, void* d_ws, size_t ws_size,
                              hipStream_t stream) {
    const float* x    = (const float*)d_in[0];
    const int*   ei   = (const int*)d_in[1];
    const float* ea   = (const float*)d_in[2];
    const int*   eib  = (const int*)d_in[3];
    const float* eab  = (const float*)d_in[4];
    const float* fc1w = (const float*)d_in[5];
    const float* fc1b = (const float*)d_in[6];
    const float* fc2w = (const float*)d_in[7];
    const float* fc2b = (const float*)d_in[8];
    const float* fc3w = (const float*)d_in[9];
    const float* fc3b = (const float*)d_in[10];
    const float* k1w1 = (const float*)d_in[11];
    const float* k1b1 = (const float*)d_in[12];
    const float* k1w2 = (const float*)d_in[13];
    const float* k1b2 = (const float*)d_in[14];
    const float* k1w3 = (const float*)d_in[15];
    const float* k1b3 = (const float*)d_in[16];
    const float* root1 = (const float*)d_in[17];
    const float* bias1 = (const float*)d_in[18];
    const float* k2w1 = (const float*)d_in[19];
    const float* k2b1 = (const float*)d_in[20];
    const float* k2w2 = (const float*)d_in[21];
    const float* k2b2 = (const float*)d_in[22];
    const float* k2w3 = (const float*)d_in[23];
    const float* k2b3 = (const float*)d_in[24];
    const float* root2 = (const float*)d_in[25];
    const float* bias2 = (const float*)d_in[26];
    float* out = (float*)d_out;

    const int N  = in_sizes[0];
    const int E  = in_sizes[2] / 6;
    const int Eb = in_sizes[4] / 6;

    // ---- workspace carve (256B aligned) ----
    char* p = (char*)d_ws;
    auto alloc = [&](size_t bytes) {
        char* r = p;
        p += (bytes + 255) & ~(size_t)255;
        return (void*)r;
    };
    float* x0   = (float*)alloc((size_t)N * 64 * 4);
    float* hA   = (float*)alloc((size_t)N * 64 * 4);
    float* hB   = (float*)alloc((size_t)N * 64 * 4);
    float* sbuf = (float*)alloc((size_t)2 * N * 64 * 4);   // s1 | s2
    float* cnt  = (float*)alloc((size_t)2 * N * 4);        // cnt1 | cnt2
    u16*   h2a  = (u16*)alloc((size_t)E * K2DIM * 2);
    u16*   h2b  = (u16*)alloc((size_t)Eb * K2DIM * 2);
    u16*   Bp1  = (u16*)alloc((size_t)KERW * K2DIM * 2);
    u16*   Bp2  = (u16*)alloc((size_t)KERW * K2DIM * 2);
    float* b3p1 = (float*)alloc((size_t)KERW * 4);
    float* b3p2 = (float*)alloc((size_t)KERW * 4);
    u16*   W1   = (u16*)alloc((size_t)E * KERW * 2);
    u16*   W2   = (u16*)alloc((size_t)Eb * KERW * 2);
    (void)ws_size;

    const int* src1 = ei;       const int* dst1 = ei + E;
    const int* src2 = eib;      const int* dst2 = eib + Eb;

    // ---- precompute phase ----
    hipMemsetAsync(cnt, 0, (size_t)2 * N * 4, stream);
    {
        int tot = E + Eb;
        count_k<<<(tot + 255) / 256, 256, 0, stream>>>(dst1, E, dst2, Eb, cnt, N);
    }
    fc1_k<<<((size_t)N * 64 + 255) / 256, 256, 0, stream>>>(x, fc1w, fc1b, x0, N);

    mlp12_k<<<E, 128, 0, stream>>>(ea, k1w1, k1b1, k1w2, k1b2, h2a, E);
    mlp12_k<<<Eb, 128, 0, stream>>>(eab, k2w1, k2b1, k2w2, k2b2, h2b, Eb);

    prep_b_k<<<(KERW * K2DIM) / 256, 256, 0, stream>>>(k1w3, k1b3, Bp1, b3p1);
    prep_b_k<<<(KERW * K2DIM) / 256, 256, 0, stream>>>(k2w3, k2b3, Bp2, b3p2);

    {
        dim3 g1((E + 127) / 128, KERW / 128);
        w3_mfma_k<<<g1, 256, 0, stream>>>(h2a, Bp1, b3p1, W1, E);
        dim3 g2((Eb + 127) / 128, KERW / 128);
        w3_mfma_k<<<g2, 256, 0, stream>>>(h2b, Bp2, b3p2, W2, Eb);
    }

    // ---- 4 message-passing layers ----
    const float* hcur = x0;
    float* bufs[2] = { hA, hB };
    for (int l = 0; l < DEPTH; ++l) {
        float* hnext = bufs[l & 1];
        hipMemsetAsync(sbuf, 0, (size_t)2 * N * 64 * 4, stream);
        msg_k<<<(E + 3) / 4, 256, 0, stream>>>(hcur, W1, src1, dst1, sbuf, E);
        msg_k<<<(Eb + 3) / 4, 256, 0, stream>>>(hcur, W2, src2, dst2, sbuf + (size_t)N * 64, Eb);
        combine_k<<<(N + 3) / 4, 256, 0, stream>>>(hcur, sbuf, cnt, root1, root2, bias1, bias2,
                                                   x0, hnext, N);
        hcur = hnext;
    }

    // ---- head ----
    head_k<<<N, 128, 0, stream>>>(hcur, fc2w, fc2b, fc3w, fc3b, out, N);
}

// Round 3
// 462.493 us; speedup vs baseline: 1.6286x; 1.0293x over previous
//
#include <hip/hip_runtime.h>
#include <hip/hip_bf16.h>

typedef unsigned short u16;
typedef unsigned int u32;

#define WIDTH 64
#define KERW 4096   // 64*64
#define K2DIM 128
#define DEPTH 4

typedef __attribute__((ext_vector_type(8))) short short8;
typedef __attribute__((ext_vector_type(4))) float f32x4;

__device__ __forceinline__ u16 f2bf(float f) {
    union { float f; u32 u; } v; v.f = f;
    u32 r = v.u + 0x7FFFu + ((v.u >> 16) & 1u);
    return (u16)(r >> 16);
}
__device__ __forceinline__ float bflo(u32 u) { return __uint_as_float(u << 16); }
__device__ __forceinline__ float bfhi(u32 u) { return __uint_as_float(u & 0xFFFF0000u); }

// ---------------- fc1: x0[n][j] = fc1_w[j]*x[n] + fc1_b[j] ----------------
__global__ void fc1_k(const float* __restrict__ x, const float* __restrict__ w,
                      const float* __restrict__ b, float* __restrict__ x0, int N) {
    int idx = blockIdx.x * 256 + threadIdx.x;
    if (idx < N * WIDTH) {
        int n = idx >> 6, j = idx & 63;
        x0[idx] = w[j] * x[n] + b[j];
    }
}

// ---------------- edge counts (scatter-mean denominators) ----------------
__global__ void count_k(const int* __restrict__ dst1, int E,
                        const int* __restrict__ dst2, int Eb,
                        float* __restrict__ cnt, int N) {
    int i = blockIdx.x * 256 + threadIdx.x;
    if (i < E) atomicAdd(&cnt[dst1[i]], 1.0f);
    else if (i < E + Eb) atomicAdd(&cnt[N + dst2[i - E]], 1.0f);
}

// ---------------- kernel-MLP layers 1+2: edge_attr[E,6] -> h2[E,128] bf16 ----------------
__global__ __launch_bounds__(128) void mlp12_k(const float* __restrict__ ea,
                                               const float* __restrict__ w1, const float* __restrict__ b1,
                                               const float* __restrict__ w2, const float* __restrict__ b2,
                                               u16* __restrict__ h2, int E) {
    __shared__ float sea[8];
    __shared__ float sh1[64];
    int e = blockIdx.x, t = threadIdx.x;
    if (t < 6) sea[t] = ea[(size_t)e * 6 + t];
    __syncthreads();
    if (t < 64) {
        float a = b1[t];
        #pragma unroll
        for (int k = 0; k < 6; ++k) a += sea[k] * w1[t * 6 + k];
        sh1[t] = fmaxf(a, 0.f);
    }
    __syncthreads();
    float a = b2[t];
    #pragma unroll 8
    for (int j = 0; j < 64; ++j) a += sh1[j] * w2[t * 64 + j];
    h2[(size_t)e * K2DIM + t] = f2bf(fmaxf(a, 0.f));
}

// ---------------- prep B panel: Bp[c][k] = bf16(w3[pr(c)][k]), b3p[c] = b3[pr(c)] ----------------
// pr(c) = (c&63)*64 + (c>>6)   (c = o*64+i so msg kernel reads [e][o][i] contiguous in i)
__global__ void prep_b_k(const float* __restrict__ w3, const float* __restrict__ b3,
                         u16* __restrict__ Bp, float* __restrict__ b3p) {
    int idx = blockIdx.x * 256 + threadIdx.x;   // 4096*128
    int c = idx >> 7, k = idx & 127;
    int pr = ((c & 63) << 6) | (c >> 6);
    Bp[idx] = f2bf(w3[(size_t)pr * 128 + k]);
    if (k == 0) b3p[c] = b3[pr];
}

// ---------------- big GEMM via MFMA, LDS-free: Wt[e][c] = h2[e].Bp[c] + b3p[c] ----------------
// K=128 single-shot. Fragments loaded straight from global (16B/lane, 4 lanes per
// 64B line). B (1MB) and the live A-tiles are L2-resident. XCD-bijective block
// swizzle keeps all 32 col-blocks of one A-tile on one XCD (A fetched once from HBM).
// 128x128 tile per block, 4 waves (2x2 of 64x64), 16x16x32 bf16 MFMA.
__global__ __launch_bounds__(256, 4) void w3_mfma_k(const u16* __restrict__ h2,  // [E][128] bf16
                                                    const u16* __restrict__ Bp,  // [4096][128] bf16
                                                    const float* __restrict__ b3p,
                                                    u16* __restrict__ Wt, int E, int nE) {
    int p = blockIdx.x;
    int xcd = p & 7, j = p >> 3;
    int t = (j >> 5) * 8 + xcd;          // e-tile (nE padded to multiple of 8 in grid)
    if (t >= nE) return;
    int eb = t << 7, cb = (j & 31) << 7;

    int lane = threadIdx.x & 63, wv = threadIdx.x >> 6;
    int wr = (wv >> 1) << 6, wc = (wv & 1) << 6;
    int lr = lane & 15, lg = lane >> 4;

    const u16* arow[4];
    const u16* brow[4];
    #pragma unroll
    for (int m = 0; m < 4; ++m) {
        int r = eb + wr + m * 16 + lr;
        if (r >= E) r = E - 1;
        arow[m] = h2 + (size_t)r * 128 + lg * 8;   // k = kk*32 + lg*8 + [0..7]
    }
    #pragma unroll
    for (int n = 0; n < 4; ++n)
        brow[n] = Bp + (size_t)(cb + wc + n * 16 + lr) * 128 + lg * 8;

    f32x4 acc[4][4] = {};
    #pragma unroll
    for (int kk = 0; kk < 4; ++kk) {
        short8 af[4], bf[4];
        #pragma unroll
        for (int m = 0; m < 4; ++m) af[m] = *(const short8*)(arow[m] + kk * 32);
        #pragma unroll
        for (int n = 0; n < 4; ++n) bf[n] = *(const short8*)(brow[n] + kk * 32);
        #pragma unroll
        for (int m = 0; m < 4; ++m)
            #pragma unroll
            for (int n = 0; n < 4; ++n)
                acc[m][n] = __builtin_amdgcn_mfma_f32_16x16x32_bf16(af[m], bf[n], acc[m][n], 0, 0, 0);
    }

    float bb[4];
    #pragma unroll
    for (int n = 0; n < 4; ++n) bb[n] = b3p[cb + wc + n * 16 + lr];

    // D layout: col = lane&15, row = (lane>>4)*4 + reg
    #pragma unroll
    for (int m = 0; m < 4; ++m) {
        #pragma unroll
        for (int r4 = 0; r4 < 4; ++r4) {
            int eg = eb + wr + m * 16 + lg * 4 + r4;
            if (eg < E) {
                u16* wp = Wt + (size_t)eg * KERW + cb + wc + lr;
                #pragma unroll
                for (int n = 0; n < 4; ++n)
                    wp[n * 16] = f2bf(acc[m][n][r4] + bb[n]);
            }
        }
    }
}

// ---------------- message + scatter-add: wave per edge ----------------
// Wt layout [e][o*64+i]: lane o reads 64 contiguous bf16 (its W column)
__global__ __launch_bounds__(256) void msg_k(const float* __restrict__ h,
                                             const u16* __restrict__ Wt,
                                             const int* __restrict__ src, const int* __restrict__ dst,
                                             float* __restrict__ s, int E) {
    __shared__ float hs[4][64];
    int w = threadIdx.x >> 6, o = threadIdx.x & 63;
    int e = blockIdx.x * 4 + w;
    bool valid = e < E;
    int ec = valid ? e : 0;
    int sv = src[ec];
    hs[w][o] = h[(size_t)sv * 64 + o];
    __syncthreads();
    const u16* wr = Wt + (size_t)ec * KERW + o * 64;
    float acc = 0.f;
    #pragma unroll
    for (int jj = 0; jj < 8; ++jj) {
        uint4 v = *(const uint4*)(wr + jj * 8);
        const float* hh = &hs[w][jj * 8];
        acc += bflo(v.x) * hh[0]; acc += bfhi(v.x) * hh[1];
        acc += bflo(v.y) * hh[2]; acc += bfhi(v.y) * hh[3];
        acc += bflo(v.z) * hh[4]; acc += bfhi(v.z) * hh[5];
        acc += bflo(v.w) * hh[6]; acc += bfhi(v.w) * hh[7];
    }
    if (valid) atomicAdd(&s[(size_t)dst[ec] * 64 + o], acc);
}

// ---------------- combine: mean + h@(root1+root2) + biases, relu, +x0 ----------------
// 16 nodes per block (root matrix staged once per 16 nodes instead of per 4)
__global__ __launch_bounds__(256) void combine_k(const float* __restrict__ h,
                                                 const float* __restrict__ s,   // [2][N][64]
                                                 const float* __restrict__ cnt, // [2][N]
                                                 const float* __restrict__ root1, const float* __restrict__ root2,
                                                 const float* __restrict__ bias1, const float* __restrict__ bias2,
                                                 const float* __restrict__ x0, float* __restrict__ hout, int N) {
    __shared__ float rs[64][64];
    __shared__ float hr[4][64];
    int t = threadIdx.x;
    for (int j = t; j < 4096; j += 256) rs[j >> 6][j & 63] = root1[j] + root2[j];
    int w = t >> 6, o = t & 63;
    float bsum = bias1[o] + bias2[o];
    __syncthreads();
    #pragma unroll
    for (int g = 0; g < 4; ++g) {
        int n = blockIdx.x * 16 + g * 4 + w;
        bool valid = n < N;
        int nc = valid ? n : 0;
        hr[w][o] = h[(size_t)nc * 64 + o];   // per-wave region: wave-lockstep, no barrier needed
        float inv1 = 1.0f / fmaxf(cnt[nc], 1.0f);
        float inv2 = 1.0f / fmaxf(cnt[N + nc], 1.0f);
        float acc = s[(size_t)nc * 64 + o] * inv1
                  + s[(size_t)(N + nc) * 64 + o] * inv2
                  + bsum;
        #pragma unroll 8
        for (int i = 0; i < 64; ++i) acc += hr[w][i] * rs[i][o];
        if (valid) hout[(size_t)n * 64 + o] = fmaxf(acc, 0.f) + x0[(size_t)n * 64 + o];
    }
}

// ---------------- head: out[n] = fc3( relu(fc2(h[n])) ) ----------------
__global__ __launch_bounds__(128) void head_k(const float* __restrict__ h,
                                              const float* __restrict__ fc2w, const float* __restrict__ fc2b,
                                              const float* __restrict__ fc3w, const float* __restrict__ fc3b,
                                              float* __restrict__ out, int N) {
    __shared__ float hr[64];
    __shared__ float red[128];
    int n = blockIdx.x, t = threadIdx.x;
    if (t < 64) hr[t] = h[(size_t)n * 64 + t];
    __syncthreads();
    float a = fc2b[t];
    #pragma unroll 8
    for (int i = 0; i < 64; ++i) a += hr[i] * fc2w[t * 64 + i];
    red[t] = fmaxf(a, 0.f) * fc3w[t];
    __syncthreads();
    if (t < 64) {
        float v = red[t] + red[t + 64];
        for (int off = 32; off; off >>= 1) v += __shfl_down(v, off);
        if (t == 0) out[n] = v + fc3b[0];
    }
}

extern "C" void kernel_launch(void* const* d_in, const int* in_sizes, int n_in,
                              void* d_out, int out_size, void* d_ws, size_t ws_size,
                              hipStream_t stream) {
    const float* x    = (const float*)d_in[0];
    const int*   ei   = (const int*)d_in[1];
    const float* ea   = (const float*)d_in[2];
    const int*   eib  = (const int*)d_in[3];
    const float* eab  = (const float*)d_in[4];
    const float* fc1w = (const float*)d_in[5];
    const float* fc1b = (const float*)d_in[6];
    const float* fc2w = (const float*)d_in[7];
    const float* fc2b = (const float*)d_in[8];
    const float* fc3w = (const float*)d_in[9];
    const float* fc3b = (const float*)d_in[10];
    const float* k1w1 = (const float*)d_in[11];
    const float* k1b1 = (const float*)d_in[12];
    const float* k1w2 = (const float*)d_in[13];
    const float* k1b2 = (const float*)d_in[14];
    const float* k1w3 = (const float*)d_in[15];
    const float* k1b3 = (const float*)d_in[16];
    const float* root1 = (const float*)d_in[17];
    const float* bias1 = (const float*)d_in[18];
    const float* k2w1 = (const float*)d_in[19];
    const float* k2b1 = (const float*)d_in[20];
    const float* k2w2 = (const float*)d_in[21];
    const float* k2b2 = (const float*)d_in[22];
    const float* k2w3 = (const float*)d_in[23];
    const float* k2b3 = (const float*)d_in[24];
    const float* root2 = (const float*)d_in[25];
    const float* bias2 = (const float*)d_in[26];
    float* out = (float*)d_out;

    const int N  = in_sizes[0];
    const int E  = in_sizes[2] / 6;
    const int Eb = in_sizes[4] / 6;

    // ---- workspace carve (256B aligned) ----
    char* p = (char*)d_ws;
    auto alloc = [&](size_t bytes) {
        char* r = p;
        p += (bytes + 255) & ~(size_t)255;
        return (void*)r;
    };
    float* x0   = (float*)alloc((size_t)N * 64 * 4);
    float* hA   = (float*)alloc((size_t)N * 64 * 4);
    float* hB   = (float*)alloc((size_t)N * 64 * 4);
    float* sbuf = (float*)alloc((size_t)2 * N * 64 * 4);   // s1 | s2
    float* cnt  = (float*)alloc((size_t)2 * N * 4);        // cnt1 | cnt2
    u16*   h2a  = (u16*)alloc((size_t)E * K2DIM * 2);
    u16*   h2b  = (u16*)alloc((size_t)Eb * K2DIM * 2);
    u16*   Bp1  = (u16*)alloc((size_t)KERW * K2DIM * 2);
    u16*   Bp2  = (u16*)alloc((size_t)KERW * K2DIM * 2);
    float* b3p1 = (float*)alloc((size_t)KERW * 4);
    float* b3p2 = (float*)alloc((size_t)KERW * 4);
    u16*   W1   = (u16*)alloc((size_t)E * KERW * 2);
    u16*   W2   = (u16*)alloc((size_t)Eb * KERW * 2);
    (void)ws_size;

    const int* src1 = ei;       const int* dst1 = ei + E;
    const int* src2 = eib;      const int* dst2 = eib + Eb;

    // ---- precompute phase ----
    hipMemsetAsync(cnt, 0, (size_t)2 * N * 4, stream);
    {
        int tot = E + Eb;
        count_k<<<(tot + 255) / 256, 256, 0, stream>>>(dst1, E, dst2, Eb, cnt, N);
    }
    fc1_k<<<((size_t)N * 64 + 255) / 256, 256, 0, stream>>>(x, fc1w, fc1b, x0, N);

    mlp12_k<<<E, 128, 0, stream>>>(ea, k1w1, k1b1, k1w2, k1b2, h2a, E);
    mlp12_k<<<Eb, 128, 0, stream>>>(eab, k2w1, k2b1, k2w2, k2b2, h2b, Eb);

    prep_b_k<<<(KERW * K2DIM) / 256, 256, 0, stream>>>(k1w3, k1b3, Bp1, b3p1);
    prep_b_k<<<(KERW * K2DIM) / 256, 256, 0, stream>>>(k2w3, k2b3, Bp2, b3p2);

    {
        int nE1 = (E + 127) / 128, nE1p = ((nE1 + 7) / 8) * 8;
        w3_mfma_k<<<nE1p * 32, 256, 0, stream>>>(h2a, Bp1, b3p1, W1, E, nE1);
        int nE2 = (Eb + 127) / 128, nE2p = ((nE2 + 7) / 8) * 8;
        w3_mfma_k<<<nE2p * 32, 256, 0, stream>>>(h2b, Bp2, b3p2, W2, Eb, nE2);
    }

    // ---- 4 message-passing layers ----
    const float* hcur = x0;
    float* bufs[2] = { hA, hB };
    for (int l = 0; l < DEPTH; ++l) {
        float* hnext = bufs[l & 1];
        hipMemsetAsync(sbuf, 0, (size_t)2 * N * 64 * 4, stream);
        msg_k<<<(E + 3) / 4, 256, 0, stream>>>(hcur, W1, src1, dst1, sbuf, E);
        msg_k<<<(Eb + 3) / 4, 256, 0, stream>>>(hcur, W2, src2, dst2, sbuf + (size_t)N * 64, Eb);
        combine_k<<<(N + 15) / 16, 256, 0, stream>>>(hcur, sbuf, cnt, root1, root2, bias1, bias2,
                                                     x0, hnext, N);
        hcur = hnext;
    }

    // ---- head ----
    head_k<<<N, 128, 0, stream>>>(hcur, fc2w, fc2b, fc3w, fc3b, out, N);
}

// Round 5
// 454.455 us; speedup vs baseline: 1.6574x; 1.0177x over previous
//
#include <hip/hip_runtime.h>
#include <hip/hip_bf16.h>

typedef unsigned short u16;
typedef unsigned int u32;

#define WIDTH 64
#define KERW 4096   // 64*64
#define K2DIM 128
#define DEPTH 4

typedef __attribute__((ext_vector_type(8))) short short8;
typedef __attribute__((ext_vector_type(4))) float f32x4;

__device__ __forceinline__ u16 f2bf(float f) {
    union { float f; u32 u; } v; v.f = f;
    u32 r = v.u + 0x7FFFu + ((v.u >> 16) & 1u);
    return (u16)(r >> 16);
}
__device__ __forceinline__ float bflo(u32 u) { return __uint_as_float(u << 16); }
__device__ __forceinline__ float bfhi(u32 u) { return __uint_as_float(u & 0xFFFF0000u); }

// Stored W layout: position o*64 + sig(i) holds W[e][i][o], sig(i) = (i&15)*4 + (i>>4).
// GEMM logical column c' = o*64 + i (plain); epilogue permutes the STORE position
// (lane's 4 n-values contiguous -> ushort4); msg_k stages h sig-permuted; bias
// array is stored sig-permuted so the epilogue can float4-load it at stored pos.

// ---------------- fc1: x0[n][j] = fc1_w[j]*x[n] + fc1_b[j] ----------------
__global__ void fc1_k(const float* __restrict__ x, const float* __restrict__ w,
                      const float* __restrict__ b, float* __restrict__ x0, int N) {
    int idx = blockIdx.x * 256 + threadIdx.x;
    if (idx < N * WIDTH) {
        int n = idx >> 6, j = idx & 63;
        x0[idx] = w[j] * x[n] + b[j];
    }
}

// ---------------- edge counts (scatter-mean denominators) ----------------
__global__ void count_k(const int* __restrict__ dst1, int E,
                        const int* __restrict__ dst2, int Eb,
                        float* __restrict__ cnt, int N) {
    int i = blockIdx.x * 256 + threadIdx.x;
    if (i < E) atomicAdd(&cnt[dst1[i]], 1.0f);
    else if (i < E + Eb) atomicAdd(&cnt[N + dst2[i - E]], 1.0f);
}

// ---------------- kernel-MLP layers 1+2: edge_attr[E,6] -> h2[E,128] bf16 ----------------
__global__ __launch_bounds__(128) void mlp12_k(const float* __restrict__ ea,
                                               const float* __restrict__ w1, const float* __restrict__ b1,
                                               const float* __restrict__ w2, const float* __restrict__ b2,
                                               u16* __restrict__ h2, int E) {
    __shared__ float sea[8];
    __shared__ float sh1[64];
    int e = blockIdx.x, t = threadIdx.x;
    if (t < 6) sea[t] = ea[(size_t)e * 6 + t];
    __syncthreads();
    if (t < 64) {
        float a = b1[t];
        #pragma unroll
        for (int k = 0; k < 6; ++k) a += sea[k] * w1[t * 6 + k];
        sh1[t] = fmaxf(a, 0.f);
    }
    __syncthreads();
    float a = b2[t];
    #pragma unroll 8
    for (int j = 0; j < 64; ++j) a += sh1[j] * w2[t * 64 + j];
    h2[(size_t)e * K2DIM + t] = f2bf(fmaxf(a, 0.f));
}

// ---------------- prep B panel ----------------
// GEMM column c' = o*64 + i  ->  Bp[c'] = w3 row (i*64 + o)   [plain transpose]
// bias stored sig-permuted: b3p[o*64 + sig(i)] = b3[i*64 + o]
__global__ void prep_b_k(const float* __restrict__ w3, const float* __restrict__ b3,
                         u16* __restrict__ Bp, float* __restrict__ b3p) {
    int idx = blockIdx.x * 256 + threadIdx.x;   // 4096*128
    int c = idx >> 7, k = idx & 127;
    int i = c & 63, o = c >> 6;
    int pr = (i << 6) | o;
    Bp[idx] = f2bf(w3[(size_t)pr * 128 + k]);
    if (k == 0) b3p[(o << 6) | ((i & 15) << 2) | (i >> 4)] = b3[pr];
}

// ---------------- big GEMM via MFMA, LDS-free: Wt = h2 . Bp + b3, bf16, sig-stored ----------------
// K=128 single-shot, fragments straight from global (L2-resident), XCD-bijective
// swizzle keeps one A-tile's 32 col-blocks on one XCD. Epilogue: lane's 4 n-values
// contiguous under sig-layout -> ushort4 stores (4 rows x 128B per wave instr).
__global__ __launch_bounds__(256, 4) void w3_mfma_k(const u16* __restrict__ h2,  // [E][128] bf16
                                                    const u16* __restrict__ Bp,  // [4096][128] bf16
                                                    const float* __restrict__ b3p,
                                                    u16* __restrict__ Wt, int E, int nE) {
    int p = blockIdx.x;
    int xcd = p & 7, j = p >> 3;
    int t = (j >> 5) * 8 + xcd;          // e-tile (nE padded to multiple of 8 in grid)
    if (t >= nE) return;
    int eb = t << 7, cb = (j & 31) << 7;

    int lane = threadIdx.x & 63, wv = threadIdx.x >> 6;
    int wr = (wv >> 1) << 6, wc = (wv & 1) << 6;
    int lr = lane & 15, lg = lane >> 4;

    const u16* arow[4];
    const u16* brow[4];
    #pragma unroll
    for (int m = 0; m < 4; ++m) {
        int r = eb + wr + m * 16 + lr;
        if (r >= E) r = E - 1;
        arow[m] = h2 + (size_t)r * 128 + lg * 8;   // k = kk*32 + lg*8 + [0..7]
    }
    #pragma unroll
    for (int n = 0; n < 4; ++n)
        brow[n] = Bp + (size_t)(cb + wc + n * 16 + lr) * 128 + lg * 8;

    f32x4 acc[4][4] = {};
    #pragma unroll
    for (int kk = 0; kk < 4; ++kk) {
        short8 af[4], bf[4];
        #pragma unroll
        for (int m = 0; m < 4; ++m) af[m] = *(const short8*)(arow[m] + kk * 32);
        #pragma unroll
        for (int n = 0; n < 4; ++n) bf[n] = *(const short8*)(brow[n] + kk * 32);
        #pragma unroll
        for (int m = 0; m < 4; ++m)
            #pragma unroll
            for (int n = 0; n < 4; ++n)
                acc[m][n] = __builtin_amdgcn_mfma_f32_16x16x32_bf16(af[m], bf[n], acc[m][n], 0, 0, 0);
    }

    // stored position for (row, GEMM col c'=cb+wc+n*16+lr) = cb + wc + lr*4 + n
    // b3p is sig-permuted, so b3p[cb+wc+lr*4+n] is exactly the bias for acc[m][n]
    float4 bb4 = *(const float4*)(b3p + cb + wc + lr * 4);

    #pragma unroll
    for (int m = 0; m < 4; ++m) {
        #pragma unroll
        for (int r4 = 0; r4 < 4; ++r4) {
            int eg = eb + wr + m * 16 + lg * 4 + r4;
            if (eg < E) {
                ushort4 pk;
                pk.x = f2bf(acc[m][0][r4] + bb4.x);
                pk.y = f2bf(acc[m][1][r4] + bb4.y);
                pk.z = f2bf(acc[m][2][r4] + bb4.z);
                pk.w = f2bf(acc[m][3][r4] + bb4.w);
                *(ushort4*)(Wt + (size_t)eg * KERW + cb + wc + lr * 4) = pk;
            }
        }
    }
}

// ---------------- message + scatter-add: wave per edge ----------------
// Wt layout [e][o*64 + sig(i)]: lane o reads 64 contiguous bf16; h staged sig-permuted
__global__ __launch_bounds__(256) void msg_k(const float* __restrict__ h,
                                             const u16* __restrict__ Wt,
                                             const int* __restrict__ src, const int* __restrict__ dst,
                                             float* __restrict__ s, int E) {
    __shared__ float hs[4][64];
    int w = threadIdx.x >> 6, o = threadIdx.x & 63;
    int e = blockIdx.x * 4 + w;
    bool valid = e < E;
    int ec = valid ? e : 0;
    int sv = src[ec];
    hs[w][((o & 15) << 2) | (o >> 4)] = h[(size_t)sv * 64 + o];   // sig-permuted staging
    __syncthreads();
    const u16* wr = Wt + (size_t)ec * KERW + o * 64;
    float acc = 0.f;
    #pragma unroll
    for (int jj = 0; jj < 8; ++jj) {
        uint4 v = *(const uint4*)(wr + jj * 8);
        const float* hh = &hs[w][jj * 8];
        acc += bflo(v.x) * hh[0]; acc += bfhi(v.x) * hh[1];
        acc += bflo(v.y) * hh[2]; acc += bfhi(v.y) * hh[3];
        acc += bflo(v.z) * hh[4]; acc += bfhi(v.z) * hh[5];
        acc += bflo(v.w) * hh[6]; acc += bfhi(v.w) * hh[7];
    }
    if (valid) atomicAdd(&s[(size_t)dst[ec] * 64 + o], acc);
}

// ---------------- combine: mean + h@(root1+root2) + biases, relu, +x0 ----------------
// 16 nodes per block (root matrix staged once per 16 nodes)
__global__ __launch_bounds__(256) void combine_k(const float* __restrict__ h,
                                                 const float* __restrict__ s,   // [2][N][64]
                                                 const float* __restrict__ cnt, // [2][N]
                                                 const float* __restrict__ root1, const float* __restrict__ root2,
                                                 const float* __restrict__ bias1, const float* __restrict__ bias2,
                                                 const float* __restrict__ x0, float* __restrict__ hout, int N) {
    __shared__ float rs[64][64];
    __shared__ float hr[4][64];
    int t = threadIdx.x;
    for (int j = t; j < 4096; j += 256) rs[j >> 6][j & 63] = root1[j] + root2[j];
    int w = t >> 6, o = t & 63;
    float bsum = bias1[o] + bias2[o];
    __syncthreads();
    #pragma unroll
    for (int g = 0; g < 4; ++g) {
        int n = blockIdx.x * 16 + g * 4 + w;
        bool valid = n < N;
        int nc = valid ? n : 0;
        hr[w][o] = h[(size_t)nc * 64 + o];   // per-wave region: wave-lockstep, no barrier needed
        float inv1 = 1.0f / fmaxf(cnt[nc], 1.0f);
        float inv2 = 1.0f / fmaxf(cnt[N + nc], 1.0f);
        float acc = s[(size_t)nc * 64 + o] * inv1
                  + s[(size_t)(N + nc) * 64 + o] * inv2
                  + bsum;
        #pragma unroll 8
        for (int i = 0; i < 64; ++i) acc += hr[w][i] * rs[i][o];
        if (valid) hout[(size_t)n * 64 + o] = fmaxf(acc, 0.f) + x0[(size_t)n * 64 + o];
    }
}

// ---------------- head: out[n] = fc3( relu(fc2(h[n])) ) ----------------
__global__ __launch_bounds__(128) void head_k(const float* __restrict__ h,
                                              const float* __restrict__ fc2w, const float* __restrict__ fc2b,
                                              const float* __restrict__ fc3w, const float* __restrict__ fc3b,
                                              float* __restrict__ out, int N) {
    __shared__ float hr[64];
    __shared__ float red[128];
    int n = blockIdx.x, t = threadIdx.x;
    if (t < 64) hr[t] = h[(size_t)n * 64 + t];
    __syncthreads();
    float a = fc2b[t];
    #pragma unroll 8
    for (int i = 0; i < 64; ++i) a += hr[i] * fc2w[t * 64 + i];
    red[t] = fmaxf(a, 0.f) * fc3w[t];
    __syncthreads();
    if (t < 64) {
        float v = red[t] + red[t + 64];
        for (int off = 32; off; off >>= 1) v += __shfl_down(v, off);
        if (t == 0) out[n] = v + fc3b[0];
    }
}

extern "C" void kernel_launch(void* const* d_in, const int* in_sizes, int n_in,
                              void* d_out, int out_size, void* d_ws, size_t ws_size,
                              hipStream_t stream) {
    const float* x    = (const float*)d_in[0];
    const int*   ei   = (const int*)d_in[1];
    const float* ea   = (const float*)d_in[2];
    const int*   eib  = (const int*)d_in[3];
    const float* eab  = (const float*)d_in[4];
    const float* fc1w = (const float*)d_in[5];
    const float* fc1b = (const float*)d_in[6];
    const float* fc2w = (const float*)d_in[7];
    const float* fc2b = (const float*)d_in[8];
    const float* fc3w = (const float*)d_in[9];
    const float* fc3b = (const float*)d_in[10];
    const float* k1w1 = (const float*)d_in[11];
    const float* k1b1 = (const float*)d_in[12];
    const float* k1w2 = (const float*)d_in[13];
    const float* k1b2 = (const float*)d_in[14];
    const float* k1w3 = (const float*)d_in[15];
    const float* k1b3 = (const float*)d_in[16];
    const float* root1 = (const float*)d_in[17];
    const float* bias1 = (const float*)d_in[18];
    const float* k2w1 = (const float*)d_in[19];
    const float* k2b1 = (const float*)d_in[20];
    const float* k2w2 = (const float*)d_in[21];
    const float* k2b2 = (const float*)d_in[22];
    const float* k2w3 = (const float*)d_in[23];
    const float* k2b3 = (const float*)d_in[24];
    const float* root2 = (const float*)d_in[25];
    const float* bias2 = (const float*)d_in[26];
    float* out = (float*)d_out;

    const int N  = in_sizes[0];
    const int E  = in_sizes[2] / 6;
    const int Eb = in_sizes[4] / 6;

    // ---- workspace carve (256B aligned) ----
    char* p = (char*)d_ws;
    auto alloc = [&](size_t bytes) {
        char* r = p;
        p += (bytes + 255) & ~(size_t)255;
        return (void*)r;
    };
    float* x0   = (float*)alloc((size_t)N * 64 * 4);
    float* hA   = (float*)alloc((size_t)N * 64 * 4);
    float* hB   = (float*)alloc((size_t)N * 64 * 4);
    float* sbuf = (float*)alloc((size_t)2 * N * 64 * 4);   // s1 | s2
    float* cnt  = (float*)alloc((size_t)2 * N * 4);        // cnt1 | cnt2
    u16*   h2a  = (u16*)alloc((size_t)E * K2DIM * 2);
    u16*   h2b  = (u16*)alloc((size_t)Eb * K2DIM * 2);
    u16*   Bp1  = (u16*)alloc((size_t)KERW * K2DIM * 2);
    u16*   Bp2  = (u16*)alloc((size_t)KERW * K2DIM * 2);
    float* b3p1 = (float*)alloc((size_t)KERW * 4);
    float* b3p2 = (float*)alloc((size_t)KERW * 4);
    u16*   W1   = (u16*)alloc((size_t)E * KERW * 2);
    u16*   W2   = (u16*)alloc((size_t)Eb * KERW * 2);
    (void)ws_size;

    const int* src1 = ei;       const int* dst1 = ei + E;
    const int* src2 = eib;      const int* dst2 = eib + Eb;

    // ---- precompute phase ----
    hipMemsetAsync(cnt, 0, (size_t)2 * N * 4, stream);
    {
        int tot = E + Eb;
        count_k<<<(tot + 255) / 256, 256, 0, stream>>>(dst1, E, dst2, Eb, cnt, N);
    }
    fc1_k<<<((size_t)N * 64 + 255) / 256, 256, 0, stream>>>(x, fc1w, fc1b, x0, N);

    mlp12_k<<<E, 128, 0, stream>>>(ea, k1w1, k1b1, k1w2, k1b2, h2a, E);
    mlp12_k<<<Eb, 128, 0, stream>>>(eab, k2w1, k2b1, k2w2, k2b2, h2b, Eb);

    prep_b_k<<<(KERW * K2DIM) / 256, 256, 0, stream>>>(k1w3, k1b3, Bp1, b3p1);
    prep_b_k<<<(KERW * K2DIM) / 256, 256, 0, stream>>>(k2w3, k2b3, Bp2, b3p2);

    {
        int nE1 = (E + 127) / 128, nE1p = ((nE1 + 7) / 8) * 8;
        w3_mfma_k<<<nE1p * 32, 256, 0, stream>>>(h2a, Bp1, b3p1, W1, E, nE1);
        int nE2 = (Eb + 127) / 128, nE2p = ((nE2 + 7) / 8) * 8;
        w3_mfma_k<<<nE2p * 32, 256, 0, stream>>>(h2b, Bp2, b3p2, W2, Eb, nE2);
    }

    // ---- 4 message-passing layers ----
    const float* hcur = x0;
    float* bufs[2] = { hA, hB };
    for (int l = 0; l < DEPTH; ++l) {
        float* hnext = bufs[l & 1];
        hipMemsetAsync(sbuf, 0, (size_t)2 * N * 64 * 4, stream);
        msg_k<<<(E + 3) / 4, 256, 0, stream>>>(hcur, W1, src1, dst1, sbuf, E);
        msg_k<<<(Eb + 3) / 4, 256, 0, stream>>>(hcur, W2, src2, dst2, sbuf + (size_t)N * 64, Eb);
        combine_k<<<(N + 15) / 16, 256, 0, stream>>>(hcur, sbuf, cnt, root1, root2, bias1, bias2,
                                                     x0, hnext, N);
        hcur = hnext;
    }

    // ---- head ----
    head_k<<<N, 128, 0, stream>>>(hcur, fc2w, fc2b, fc3w, fc3b, out, N);
}

// Round 6
// 389.066 us; speedup vs baseline: 1.9359x; 1.1681x over previous
//
#include <hip/hip_runtime.h>
#include <hip/hip_bf16.h>

typedef unsigned short u16;
typedef unsigned int u32;

#define WIDTH 64
#define KERW 4096   // 64*64
#define K2DIM 128
#define DEPTH 4

typedef __attribute__((ext_vector_type(8))) short short8;
typedef __attribute__((ext_vector_type(4))) float f32x4;

__device__ __forceinline__ u16 f2bf(float f) {
    union { float f; u32 u; } v; v.f = f;
    u32 r = v.u + 0x7FFFu + ((v.u >> 16) & 1u);
    return (u16)(r >> 16);
}
__device__ __forceinline__ float bflo(u32 u) { return __uint_as_float(u << 16); }
__device__ __forceinline__ float bfhi(u32 u) { return __uint_as_float(u & 0xFFFF0000u); }

// Stored W layout (UNCHANGED from passing R4): pos o*64 + sig(i) holds W[e][i][o],
// sig(i) = (i&15)*4 + (i>>4).
// NEW: h2 / Bp are fragment-packed so GEMM loads are wave-contiguous:
//   group g = row>>4 (16 rows x 128 k = 4KB), idx_u16(row,k) =
//     g*2048 + (k>>5)*512 + lane(row,k)*8 + (k&7),  lane = (row&15) + 16*((k>>3)&3)
//   => af/bf load = base + lane*16B, one contiguous 1KB per wave instruction.

// ---------------- fc1: x0[n][j] = fc1_w[j]*x[n] + fc1_b[j] ----------------
__global__ void fc1_k(const float* __restrict__ x, const float* __restrict__ w,
                      const float* __restrict__ b, float* __restrict__ x0, int N) {
    int idx = blockIdx.x * 256 + threadIdx.x;
    if (idx < N * WIDTH) {
        int n = idx >> 6, j = idx & 63;
        x0[idx] = w[j] * x[n] + b[j];
    }
}

// ---------------- edge counts (scatter-mean denominators) ----------------
__global__ void count_k(const int* __restrict__ dst1, int E,
                        const int* __restrict__ dst2, int Eb,
                        float* __restrict__ cnt, int N) {
    int i = blockIdx.x * 256 + threadIdx.x;
    if (i < E) atomicAdd(&cnt[dst1[i]], 1.0f);
    else if (i < E + Eb) atomicAdd(&cnt[N + dst2[i - E]], 1.0f);
}

// ---------------- kernel-MLP layers 1+2: edge_attr[E,6] -> h2 packed bf16 ----------------
__global__ __launch_bounds__(128) void mlp12_k(const float* __restrict__ ea,
                                               const float* __restrict__ w1, const float* __restrict__ b1,
                                               const float* __restrict__ w2, const float* __restrict__ b2,
                                               u16* __restrict__ h2p, int E) {
    __shared__ float sea[8];
    __shared__ float sh1[64];
    int e = blockIdx.x, t = threadIdx.x;
    if (t < 6) sea[t] = ea[(size_t)e * 6 + t];
    __syncthreads();
    if (t < 64) {
        float a = b1[t];
        #pragma unroll
        for (int k = 0; k < 6; ++k) a += sea[k] * w1[t * 6 + k];
        sh1[t] = fmaxf(a, 0.f);
    }
    __syncthreads();
    float a = b2[t];
    #pragma unroll 8
    for (int j = 0; j < 64; ++j) a += sh1[j] * w2[t * 64 + j];
    // fragment-packed store (k = t)
    size_t idx = (size_t)(e >> 4) * 2048 + (t >> 5) * 512
               + (((e & 15) + 16 * ((t >> 3) & 3)) << 3) + (t & 7);
    h2p[idx] = f2bf(fmaxf(a, 0.f));
}

// ---------------- prep B panel (fragment-packed) + sig-permuted bias ----------------
// GEMM column c = o*64 + i  ->  value = w3[i*64+o][k]
__global__ void prep_b_k(const float* __restrict__ w3, const float* __restrict__ b3,
                         u16* __restrict__ Bp, float* __restrict__ b3p) {
    int idx = blockIdx.x * 256 + threadIdx.x;   // 4096*128
    int c = idx >> 7, k = idx & 127;
    int i = c & 63, o = c >> 6;
    int pr = (i << 6) | o;
    size_t w = (size_t)(c >> 4) * 2048 + (k >> 5) * 512
             + (((c & 15) + 16 * ((k >> 3) & 3)) << 3) + (k & 7);
    Bp[w] = f2bf(w3[(size_t)pr * 128 + k]);
    if (k == 0) b3p[(o << 6) | ((i & 15) << 2) | (i >> 4)] = b3[pr];
}

// ---------------- big GEMM via MFMA, LDS-free, packed operands ----------------
// K=128 single-shot; every fragment load is 1KB wave-contiguous; XCD-bijective
// swizzle keeps one A-tile's 32 col-blocks on one XCD; sig-layout ushort4 stores.
__global__ __launch_bounds__(256, 4) void w3_mfma_k(const u16* __restrict__ h2p,
                                                    const u16* __restrict__ Bp,
                                                    const float* __restrict__ b3p,
                                                    u16* __restrict__ Wt, int E, int nE) {
    int p = blockIdx.x;
    int xcd = p & 7, j = p >> 3;
    int t = (j >> 5) * 8 + xcd;          // e-tile (grid padded to x8 tiles, zero-padded data)
    if (t >= nE) return;
    int eb = t << 7, cb = (j & 31) << 7;

    int lane = threadIdx.x & 63, wv = threadIdx.x >> 6;
    int wr = (wv >> 1) << 6, wc = (wv & 1) << 6;
    int lr = lane & 15, lg = lane >> 4;

    const u16* abase = h2p + (size_t)((eb + wr) >> 4) * 2048 + lane * 8;
    const u16* bbase = Bp  + (size_t)((cb + wc) >> 4) * 2048 + lane * 8;

    f32x4 acc[4][4] = {};
    #pragma unroll
    for (int kk = 0; kk < 4; ++kk) {
        short8 af[4], bf[4];
        #pragma unroll
        for (int m = 0; m < 4; ++m) af[m] = *(const short8*)(abase + m * 2048 + kk * 512);
        #pragma unroll
        for (int n = 0; n < 4; ++n) bf[n] = *(const short8*)(bbase + n * 2048 + kk * 512);
        #pragma unroll
        for (int m = 0; m < 4; ++m)
            #pragma unroll
            for (int n = 0; n < 4; ++n)
                acc[m][n] = __builtin_amdgcn_mfma_f32_16x16x32_bf16(af[m], bf[n], acc[m][n], 0, 0, 0);
    }

    // stored position for (row, GEMM col cb+wc+n*16+lr) = cb + wc + lr*4 + n
    float4 bb4 = *(const float4*)(b3p + cb + wc + lr * 4);

    #pragma unroll
    for (int m = 0; m < 4; ++m) {
        #pragma unroll
        for (int r4 = 0; r4 < 4; ++r4) {
            int eg = eb + wr + m * 16 + lg * 4 + r4;
            if (eg < E) {
                ushort4 pk;
                pk.x = f2bf(acc[m][0][r4] + bb4.x);
                pk.y = f2bf(acc[m][1][r4] + bb4.y);
                pk.z = f2bf(acc[m][2][r4] + bb4.z);
                pk.w = f2bf(acc[m][3][r4] + bb4.w);
                *(ushort4*)(Wt + (size_t)eg * KERW + cb + wc + lr * 4) = pk;
            }
        }
    }
}

// ---------------- message + scatter-add: wave per edge, contiguous W reads ----------------
// Lane l reads 16B at byte l*16 + jj*1024 -> covers o = jj*8+(l>>3), q=(l&7)*8+[0..8).
// hs is sig-staged, so lane's h values are hs[(l&7)*8 + j]. Butterfly-reduce over
// lanes differing in l&7; lane outputs o = ((l&7)<<3)|(l>>3) (bijective).
__global__ __launch_bounds__(256) void msg_k(const float* __restrict__ h,
                                             const u16* __restrict__ Wt,
                                             const int* __restrict__ src, const int* __restrict__ dst,
                                             float* __restrict__ s, int E) {
    __shared__ float hs[4][64];
    int w = threadIdx.x >> 6, l = threadIdx.x & 63;
    int e = blockIdx.x * 4 + w;
    bool valid = e < E;
    int ec = valid ? e : 0;
    int sv = src[ec];
    hs[w][((l & 15) << 2) | (l >> 4)] = h[(size_t)sv * 64 + l];   // sig-permuted staging
    __syncthreads();
    float4 h0 = *(const float4*)&hs[w][(l & 7) * 8];
    float4 h1 = *(const float4*)&hs[w][(l & 7) * 8 + 4];
    const char* base = (const char*)(Wt + (size_t)ec * KERW) + l * 16;
    float acc[8];
    #pragma unroll
    for (int jj = 0; jj < 8; ++jj) {
        uint4 v = *(const uint4*)(base + jj * 1024);
        float a;
        a  = bflo(v.x) * h0.x; a += bfhi(v.x) * h0.y;
        a += bflo(v.y) * h0.z; a += bfhi(v.y) * h0.w;
        a += bflo(v.z) * h1.x; a += bfhi(v.z) * h1.y;
        a += bflo(v.w) * h1.z; a += bfhi(v.w) * h1.w;
        acc[jj] = a;
    }
    #pragma unroll
    for (int jj = 0; jj < 8; ++jj) {
        acc[jj] += __shfl_xor(acc[jj], 1, 64);
        acc[jj] += __shfl_xor(acc[jj], 2, 64);
        acc[jj] += __shfl_xor(acc[jj], 4, 64);
    }
    int c = l & 7;
    float val = acc[0];
    #pragma unroll
    for (int jj = 1; jj < 8; ++jj) val = (c == jj) ? acc[jj] : val;   // static idx
    if (valid) atomicAdd(&s[(size_t)dst[ec] * 64 + ((c << 3) | (l >> 3))], val);
}

// ---------------- combine: mean + h@(root1+root2) + biases, relu, +x0 ----------------
__global__ __launch_bounds__(256) void combine_k(const float* __restrict__ h,
                                                 const float* __restrict__ s,   // [2][N][64]
                                                 const float* __restrict__ cnt, // [2][N]
                                                 const float* __restrict__ root1, const float* __restrict__ root2,
                                                 const float* __restrict__ bias1, const float* __restrict__ bias2,
                                                 const float* __restrict__ x0, float* __restrict__ hout, int N) {
    __shared__ float rs[64][64];
    __shared__ float hr[4][64];
    int t = threadIdx.x;
    for (int j = t; j < 4096; j += 256) rs[j >> 6][j & 63] = root1[j] + root2[j];
    int w = t >> 6, o = t & 63;
    float bsum = bias1[o] + bias2[o];
    __syncthreads();
    #pragma unroll
    for (int g = 0; g < 4; ++g) {
        int n = blockIdx.x * 16 + g * 4 + w;
        bool valid = n < N;
        int nc = valid ? n : 0;
        hr[w][o] = h[(size_t)nc * 64 + o];   // wave-private region, lockstep
        float inv1 = 1.0f / fmaxf(cnt[nc], 1.0f);
        float inv2 = 1.0f / fmaxf(cnt[N + nc], 1.0f);
        float acc = s[(size_t)nc * 64 + o] * inv1
                  + s[(size_t)(N + nc) * 64 + o] * inv2
                  + bsum;
        #pragma unroll 8
        for (int i = 0; i < 64; ++i) acc += hr[w][i] * rs[i][o];
        if (valid) hout[(size_t)n * 64 + o] = fmaxf(acc, 0.f) + x0[(size_t)n * 64 + o];
    }
}

// ---------------- head: out[n] = fc3( relu(fc2(h[n])) ) ----------------
__global__ __launch_bounds__(128) void head_k(const float* __restrict__ h,
                                              const float* __restrict__ fc2w, const float* __restrict__ fc2b,
                                              const float* __restrict__ fc3w, const float* __restrict__ fc3b,
                                              float* __restrict__ out, int N) {
    __shared__ float hr[64];
    __shared__ float red[128];
    int n = blockIdx.x, t = threadIdx.x;
    if (t < 64) hr[t] = h[(size_t)n * 64 + t];
    __syncthreads();
    float a = fc2b[t];
    #pragma unroll 8
    for (int i = 0; i < 64; ++i) a += hr[i] * fc2w[t * 64 + i];
    red[t] = fmaxf(a, 0.f) * fc3w[t];
    __syncthreads();
    if (t < 64) {
        float v = red[t] + red[t + 64];
        for (int off = 32; off; off >>= 1) v += __shfl_down(v, off);
        if (t == 0) out[n] = v + fc3b[0];
    }
}

extern "C" void kernel_launch(void* const* d_in, const int* in_sizes, int n_in,
                              void* d_out, int out_size, void* d_ws, size_t ws_size,
                              hipStream_t stream) {
    const float* x    = (const float*)d_in[0];
    const int*   ei   = (const int*)d_in[1];
    const float* ea   = (const float*)d_in[2];
    const int*   eib  = (const int*)d_in[3];
    const float* eab  = (const float*)d_in[4];
    const float* fc1w = (const float*)d_in[5];
    const float* fc1b = (const float*)d_in[6];
    const float* fc2w = (const float*)d_in[7];
    const float* fc2b = (const float*)d_in[8];
    const float* fc3w = (const float*)d_in[9];
    const float* fc3b = (const float*)d_in[10];
    const float* k1w1 = (const float*)d_in[11];
    const float* k1b1 = (const float*)d_in[12];
    const float* k1w2 = (const float*)d_in[13];
    const float* k1b2 = (const float*)d_in[14];
    const float* k1w3 = (const float*)d_in[15];
    const float* k1b3 = (const float*)d_in[16];
    const float* root1 = (const float*)d_in[17];
    const float* bias1 = (const float*)d_in[18];
    const float* k2w1 = (const float*)d_in[19];
    const float* k2b1 = (const float*)d_in[20];
    const float* k2w2 = (const float*)d_in[21];
    const float* k2b2 = (const float*)d_in[22];
    const float* k2w3 = (const float*)d_in[23];
    const float* k2b3 = (const float*)d_in[24];
    const float* root2 = (const float*)d_in[25];
    const float* bias2 = (const float*)d_in[26];
    float* out = (float*)d_out;

    const int N  = in_sizes[0];
    const int E  = in_sizes[2] / 6;
    const int Eb = in_sizes[4] / 6;

    const int nE1 = (E + 127) / 128,  nE1p = ((nE1 + 7) / 8) * 8;
    const int nE2 = (Eb + 127) / 128, nE2p = ((nE2 + 7) / 8) * 8;

    // ---- workspace carve (256B aligned) ----
    char* p = (char*)d_ws;
    auto alloc = [&](size_t bytes) {
        char* r = p;
        p += (bytes + 255) & ~(size_t)255;
        return (void*)r;
    };
    float* x0   = (float*)alloc((size_t)N * 64 * 4);
    float* hA   = (float*)alloc((size_t)N * 64 * 4);
    float* hB   = (float*)alloc((size_t)N * 64 * 4);
    float* sbuf = (float*)alloc((size_t)2 * N * 64 * 4);   // s1 | s2
    float* cnt  = (float*)alloc((size_t)2 * N * 4);        // cnt1 | cnt2
    size_t h2aBytes = (size_t)nE1p * 128 * K2DIM * 2;      // packed, padded rows
    size_t h2bBytes = (size_t)nE2p * 128 * K2DIM * 2;
    u16*   h2a  = (u16*)alloc(h2aBytes);
    u16*   h2b  = (u16*)alloc(h2bBytes);
    u16*   Bp1  = (u16*)alloc((size_t)KERW * K2DIM * 2);
    u16*   Bp2  = (u16*)alloc((size_t)KERW * K2DIM * 2);
    float* b3p1 = (float*)alloc((size_t)KERW * 4);
    float* b3p2 = (float*)alloc((size_t)KERW * 4);
    u16*   W1   = (u16*)alloc((size_t)E * KERW * 2);
    u16*   W2   = (u16*)alloc((size_t)Eb * KERW * 2);
    (void)ws_size;

    const int* src1 = ei;       const int* dst1 = ei + E;
    const int* src2 = eib;      const int* dst2 = eib + Eb;

    // ---- precompute phase ----
    hipMemsetAsync(cnt, 0, (size_t)2 * N * 4, stream);
    hipMemsetAsync(h2a, 0, h2aBytes, stream);   // zero pad rows for clamp-free GEMM
    hipMemsetAsync(h2b, 0, h2bBytes, stream);
    {
        int tot = E + Eb;
        count_k<<<(tot + 255) / 256, 256, 0, stream>>>(dst1, E, dst2, Eb, cnt, N);
    }
    fc1_k<<<((size_t)N * 64 + 255) / 256, 256, 0, stream>>>(x, fc1w, fc1b, x0, N);

    mlp12_k<<<E, 128, 0, stream>>>(ea, k1w1, k1b1, k1w2, k1b2, h2a, E);
    mlp12_k<<<Eb, 128, 0, stream>>>(eab, k2w1, k2b1, k2w2, k2b2, h2b, Eb);

    prep_b_k<<<(KERW * K2DIM) / 256, 256, 0, stream>>>(k1w3, k1b3, Bp1, b3p1);
    prep_b_k<<<(KERW * K2DIM) / 256, 256, 0, stream>>>(k2w3, k2b3, Bp2, b3p2);

    w3_mfma_k<<<nE1p * 32, 256, 0, stream>>>(h2a, Bp1, b3p1, W1, E, nE1);
    w3_mfma_k<<<nE2p * 32, 256, 0, stream>>>(h2b, Bp2, b3p2, W2, Eb, nE2);

    // ---- 4 message-passing layers ----
    const float* hcur = x0;
    float* bufs[2] = { hA, hB };
    for (int l = 0; l < DEPTH; ++l) {
        float* hnext = bufs[l & 1];
        hipMemsetAsync(sbuf, 0, (size_t)2 * N * 64 * 4, stream);
        msg_k<<<(E + 3) / 4, 256, 0, stream>>>(hcur, W1, src1, dst1, sbuf, E);
        msg_k<<<(Eb + 3) / 4, 256, 0, stream>>>(hcur, W2, src2, dst2, sbuf + (size_t)N * 64, Eb);
        combine_k<<<(N + 15) / 16, 256, 0, stream>>>(hcur, sbuf, cnt, root1, root2, bias1, bias2,
                                                     x0, hnext, N);
        hcur = hnext;
    }

    // ---- head ----
    head_k<<<N, 128, 0, stream>>>(hcur, fc2w, fc2b, fc3w, fc3b, out, N);
}

// Round 7
// 321.360 us; speedup vs baseline: 2.3438x; 1.2107x over previous
//
#include <hip/hip_runtime.h>
#include <hip/hip_bf16.h>

typedef unsigned short u16;
typedef unsigned int u32;

#define WIDTH 64
#define KERW 4096   // 64*64
#define K2DIM 128
#define DEPTH 4
#define MEB 16      // edges per mlp12 block

typedef __attribute__((ext_vector_type(8))) short short8;
typedef __attribute__((ext_vector_type(4))) float f32x4;

__device__ __forceinline__ u16 f2bf(float f) {
    union { float f; u32 u; } v; v.f = f;
    u32 r = v.u + 0x7FFFu + ((v.u >> 16) & 1u);
    return (u16)(r >> 16);
}
__device__ __forceinline__ float bflo(u32 u) { return __uint_as_float(u << 16); }
__device__ __forceinline__ float bfhi(u32 u) { return __uint_as_float(u & 0xFFFF0000u); }

// Stored W layout: pos o*64 + sig(i) holds W[e][i][o], sig(i) = (i&15)*4 + (i>>4).
// h2 / Bp fragment-packed: idx_u16(row,k) = (row>>4)*2048 + (k>>5)*512
//   + ((row&15) + 16*((k>>3)&3))*8 + (k&7)   => GEMM loads are 1KB wave-contiguous.

// ---------------- fc1: x0[n][j] = fc1_w[j]*x[n] + fc1_b[j] ----------------
__global__ void fc1_k(const float* __restrict__ x, const float* __restrict__ w,
                      const float* __restrict__ b, float* __restrict__ x0, int N) {
    int idx = blockIdx.x * 256 + threadIdx.x;
    if (idx < N * WIDTH) {
        int n = idx >> 6, j = idx & 63;
        x0[idx] = w[j] * x[n] + b[j];
    }
}

// ---------------- edge counts (scatter-mean denominators) ----------------
__global__ void count_k(const int* __restrict__ dst1, int E,
                        const int* __restrict__ dst2, int Eb,
                        float* __restrict__ cnt, int N) {
    int i = blockIdx.x * 256 + threadIdx.x;
    if (i < E) atomicAdd(&cnt[dst1[i]], 1.0f);
    else if (i < E + Eb) atomicAdd(&cnt[N + dst2[i - E]], 1.0f);
}

// ---------------- kernel-MLP layers 1+2: edge_attr -> h2 packed bf16 ----------------
// 16 edges/block; w2 staged once per block in LDS (transposed, bf16, stride-136);
// phase2: lane owns 8 consecutive outputs -> 1 ds_read_b128 + 1 broadcast per j.
__global__ __launch_bounds__(256) void mlp12_k(const float* __restrict__ ea,
                                               const float* __restrict__ w1, const float* __restrict__ b1,
                                               const float* __restrict__ w2, const float* __restrict__ b2,
                                               u16* __restrict__ h2p, int E) {
    __shared__ u16   w2b[64 * 136];   // [j][o], pad 136 for conflict-free b128 reads
    __shared__ float h1s[MEB * 65];   // [el][j], stride 65
    __shared__ float w1s[64 * 6];
    __shared__ float b1s[64];
    __shared__ float b2s[128];
    __shared__ float eas[MEB * 6];
    int t = threadIdx.x;
    int e0 = blockIdx.x * MEB;
    // stage weights
    for (int i = t; i < 8192; i += 256)          // w2[o*64+j] -> w2b[j*136+o]
        w2b[(i & 63) * 136 + (i >> 6)] = f2bf(w2[i]);
    for (int i = t; i < 384; i += 256) w1s[i] = w1[i];
    if (t < 64) b1s[t] = b1[t];
    if (t < 128) b2s[t] = b2[t];
    {
        int ne = min(MEB, E - e0) * 6;
        if (t < ne) eas[t] = ea[(size_t)e0 * 6 + t];
    }
    __syncthreads();
    // phase 1: h1[el][o] for 16 edges
    for (int id = t; id < MEB * 64; id += 256) {
        int el = id >> 6, o = id & 63;
        float a = b1s[o];
        #pragma unroll
        for (int k = 0; k < 6; ++k) a += eas[el * 6 + k] * w1s[o * 6 + k];
        h1s[el * 65 + o] = fmaxf(a, 0.f);
    }
    __syncthreads();
    // phase 2: h2[el][og..og+7] per thread (256 tasks = 1 pass)
    int el = t >> 4, og = (t & 15) * 8;
    int e = e0 + el;
    float acc[8];
    #pragma unroll
    for (int c = 0; c < 8; ++c) acc[c] = b2s[og + c];
    const float* h1r = &h1s[el * 65];
    #pragma unroll 8
    for (int j = 0; j < 64; ++j) {
        float hj = h1r[j];
        uint4 v = *(const uint4*)&w2b[j * 136 + og];
        acc[0] += bflo(v.x) * hj; acc[1] += bfhi(v.x) * hj;
        acc[2] += bflo(v.y) * hj; acc[3] += bfhi(v.y) * hj;
        acc[4] += bflo(v.z) * hj; acc[5] += bfhi(v.z) * hj;
        acc[6] += bflo(v.w) * hj; acc[7] += bfhi(v.w) * hj;
    }
    if (e < E) {
        // packed store: k = og..og+7 are contiguous u16 in the fragment layout
        size_t idx = (size_t)(e >> 4) * 2048 + (og >> 5) * 512
                   + (((e & 15) + 16 * ((og >> 3) & 3)) << 3);
        ushort4 p0, p1;
        p0.x = f2bf(fmaxf(acc[0], 0.f)); p0.y = f2bf(fmaxf(acc[1], 0.f));
        p0.z = f2bf(fmaxf(acc[2], 0.f)); p0.w = f2bf(fmaxf(acc[3], 0.f));
        p1.x = f2bf(fmaxf(acc[4], 0.f)); p1.y = f2bf(fmaxf(acc[5], 0.f));
        p1.z = f2bf(fmaxf(acc[6], 0.f)); p1.w = f2bf(fmaxf(acc[7], 0.f));
        *(ushort4*)(h2p + idx)     = p0;
        *(ushort4*)(h2p + idx + 4) = p1;
    }
}

// ---------------- prep B panel (fragment-packed) + sig-permuted bias ----------------
// GEMM column c = o*64 + i  ->  value = w3[i*64+o][k]
__global__ void prep_b_k(const float* __restrict__ w3, const float* __restrict__ b3,
                         u16* __restrict__ Bp, float* __restrict__ b3p) {
    int idx = blockIdx.x * 256 + threadIdx.x;   // 4096*128
    int c = idx >> 7, k = idx & 127;
    int i = c & 63, o = c >> 6;
    int pr = (i << 6) | o;
    size_t w = (size_t)(c >> 4) * 2048 + (k >> 5) * 512
             + (((c & 15) + 16 * ((k >> 3) & 3)) << 3) + (k & 7);
    Bp[w] = f2bf(w3[(size_t)pr * 128 + k]);
    if (k == 0) b3p[(o << 6) | ((i & 15) << 2) | (i >> 4)] = b3[pr];
}

// ---------------- big GEMM via MFMA, LDS-free, packed operands ----------------
__global__ __launch_bounds__(256, 4) void w3_mfma_k(const u16* __restrict__ h2p,
                                                    const u16* __restrict__ Bp,
                                                    const float* __restrict__ b3p,
                                                    u16* __restrict__ Wt, int E, int nE) {
    int p = blockIdx.x;
    int xcd = p & 7, j = p >> 3;
    int t = (j >> 5) * 8 + xcd;          // e-tile (grid padded to x8 tiles, zero-padded data)
    if (t >= nE) return;
    int eb = t << 7, cb = (j & 31) << 7;

    int lane = threadIdx.x & 63, wv = threadIdx.x >> 6;
    int wr = (wv >> 1) << 6, wc = (wv & 1) << 6;
    int lr = lane & 15, lg = lane >> 4;

    const u16* abase = h2p + (size_t)((eb + wr) >> 4) * 2048 + lane * 8;
    const u16* bbase = Bp  + (size_t)((cb + wc) >> 4) * 2048 + lane * 8;

    f32x4 acc[4][4] = {};
    #pragma unroll
    for (int kk = 0; kk < 4; ++kk) {
        short8 af[4], bf[4];
        #pragma unroll
        for (int m = 0; m < 4; ++m) af[m] = *(const short8*)(abase + m * 2048 + kk * 512);
        #pragma unroll
        for (int n = 0; n < 4; ++n) bf[n] = *(const short8*)(bbase + n * 2048 + kk * 512);
        #pragma unroll
        for (int m = 0; m < 4; ++m)
            #pragma unroll
            for (int n = 0; n < 4; ++n)
                acc[m][n] = __builtin_amdgcn_mfma_f32_16x16x32_bf16(af[m], bf[n], acc[m][n], 0, 0, 0);
    }

    float4 bb4 = *(const float4*)(b3p + cb + wc + lr * 4);

    #pragma unroll
    for (int m = 0; m < 4; ++m) {
        #pragma unroll
        for (int r4 = 0; r4 < 4; ++r4) {
            int eg = eb + wr + m * 16 + lg * 4 + r4;
            if (eg < E) {
                ushort4 pk;
                pk.x = f2bf(acc[m][0][r4] + bb4.x);
                pk.y = f2bf(acc[m][1][r4] + bb4.y);
                pk.z = f2bf(acc[m][2][r4] + bb4.z);
                pk.w = f2bf(acc[m][3][r4] + bb4.w);
                *(ushort4*)(Wt + (size_t)eg * KERW + cb + wc + lr * 4) = pk;
            }
        }
    }
}

// ---------------- message + scatter-add: wave per edge, contiguous W reads ----------------
__global__ __launch_bounds__(256) void msg_k(const float* __restrict__ h,
                                             const u16* __restrict__ Wt,
                                             const int* __restrict__ src, const int* __restrict__ dst,
                                             float* __restrict__ s, int E) {
    __shared__ float hs[4][64];
    int w = threadIdx.x >> 6, l = threadIdx.x & 63;
    int e = blockIdx.x * 4 + w;
    bool valid = e < E;
    int ec = valid ? e : 0;
    int sv = src[ec];
    hs[w][((l & 15) << 2) | (l >> 4)] = h[(size_t)sv * 64 + l];   // sig-permuted staging
    __syncthreads();
    float4 h0 = *(const float4*)&hs[w][(l & 7) * 8];
    float4 h1 = *(const float4*)&hs[w][(l & 7) * 8 + 4];
    const char* base = (const char*)(Wt + (size_t)ec * KERW) + l * 16;
    float acc[8];
    #pragma unroll
    for (int jj = 0; jj < 8; ++jj) {
        uint4 v = *(const uint4*)(base + jj * 1024);
        float a;
        a  = bflo(v.x) * h0.x; a += bfhi(v.x) * h0.y;
        a += bflo(v.y) * h0.z; a += bfhi(v.y) * h0.w;
        a += bflo(v.z) * h1.x; a += bfhi(v.z) * h1.y;
        a += bflo(v.w) * h1.z; a += bfhi(v.w) * h1.w;
        acc[jj] = a;
    }
    #pragma unroll
    for (int jj = 0; jj < 8; ++jj) {
        acc[jj] += __shfl_xor(acc[jj], 1, 64);
        acc[jj] += __shfl_xor(acc[jj], 2, 64);
        acc[jj] += __shfl_xor(acc[jj], 4, 64);
    }
    int c = l & 7;
    float val = acc[0];
    #pragma unroll
    for (int jj = 1; jj < 8; ++jj) val = (c == jj) ? acc[jj] : val;   // static idx
    if (valid) atomicAdd(&s[(size_t)dst[ec] * 64 + ((c << 3) | (l >> 3))], val);
}

// ---------------- combine: mean + h@(root1+root2) + biases, relu, +x0 ----------------
__global__ __launch_bounds__(256) void combine_k(const float* __restrict__ h,
                                                 const float* __restrict__ s,   // [2][N][64]
                                                 const float* __restrict__ cnt, // [2][N]
                                                 const float* __restrict__ root1, const float* __restrict__ root2,
                                                 const float* __restrict__ bias1, const float* __restrict__ bias2,
                                                 const float* __restrict__ x0, float* __restrict__ hout, int N) {
    __shared__ float rs[64][64];
    __shared__ float hr[4][64];
    int t = threadIdx.x;
    for (int j = t; j < 4096; j += 256) rs[j >> 6][j & 63] = root1[j] + root2[j];
    int w = t >> 6, o = t & 63;
    float bsum = bias1[o] + bias2[o];
    __syncthreads();
    #pragma unroll
    for (int g = 0; g < 4; ++g) {
        int n = blockIdx.x * 16 + g * 4 + w;
        bool valid = n < N;
        int nc = valid ? n : 0;
        hr[w][o] = h[(size_t)nc * 64 + o];   // wave-private region, lockstep
        float inv1 = 1.0f / fmaxf(cnt[nc], 1.0f);
        float inv2 = 1.0f / fmaxf(cnt[N + nc], 1.0f);
        float acc = s[(size_t)nc * 64 + o] * inv1
                  + s[(size_t)(N + nc) * 64 + o] * inv2
                  + bsum;
        #pragma unroll 8
        for (int i = 0; i < 64; ++i) acc += hr[w][i] * rs[i][o];
        if (valid) hout[(size_t)n * 64 + o] = fmaxf(acc, 0.f) + x0[(size_t)n * 64 + o];
    }
}

// ---------------- head: out[n] = fc3( relu(fc2(h[n])) ) ----------------
__global__ __launch_bounds__(128) void head_k(const float* __restrict__ h,
                                              const float* __restrict__ fc2w, const float* __restrict__ fc2b,
                                              const float* __restrict__ fc3w, const float* __restrict__ fc3b,
                                              float* __restrict__ out, int N) {
    __shared__ float hr[64];
    __shared__ float red[128];
    int n = blockIdx.x, t = threadIdx.x;
    if (t < 64) hr[t] = h[(size_t)n * 64 + t];
    __syncthreads();
    float a = fc2b[t];
    #pragma unroll 8
    for (int i = 0; i < 64; ++i) a += hr[i] * fc2w[t * 64 + i];
    red[t] = fmaxf(a, 0.f) * fc3w[t];
    __syncthreads();
    if (t < 64) {
        float v = red[t] + red[t + 64];
        for (int off = 32; off; off >>= 1) v += __shfl_down(v, off);
        if (t == 0) out[n] = v + fc3b[0];
    }
}

extern "C" void kernel_launch(void* const* d_in, const int* in_sizes, int n_in,
                              void* d_out, int out_size, void* d_ws, size_t ws_size,
                              hipStream_t stream) {
    const float* x    = (const float*)d_in[0];
    const int*   ei   = (const int*)d_in[1];
    const float* ea   = (const float*)d_in[2];
    const int*   eib  = (const int*)d_in[3];
    const float* eab  = (const float*)d_in[4];
    const float* fc1w = (const float*)d_in[5];
    const float* fc1b = (const float*)d_in[6];
    const float* fc2w = (const float*)d_in[7];
    const float* fc2b = (const float*)d_in[8];
    const float* fc3w = (const float*)d_in[9];
    const float* fc3b = (const float*)d_in[10];
    const float* k1w1 = (const float*)d_in[11];
    const float* k1b1 = (const float*)d_in[12];
    const float* k1w2 = (const float*)d_in[13];
    const float* k1b2 = (const float*)d_in[14];
    const float* k1w3 = (const float*)d_in[15];
    const float* k1b3 = (const float*)d_in[16];
    const float* root1 = (const float*)d_in[17];
    const float* bias1 = (const float*)d_in[18];
    const float* k2w1 = (const float*)d_in[19];
    const float* k2b1 = (const float*)d_in[20];
    const float* k2w2 = (const float*)d_in[21];
    const float* k2b2 = (const float*)d_in[22];
    const float* k2w3 = (const float*)d_in[23];
    const float* k2b3 = (const float*)d_in[24];
    const float* root2 = (const float*)d_in[25];
    const float* bias2 = (const float*)d_in[26];
    float* out = (float*)d_out;

    const int N  = in_sizes[0];
    const int E  = in_sizes[2] / 6;
    const int Eb = in_sizes[4] / 6;

    const int nE1 = (E + 127) / 128,  nE1p = ((nE1 + 7) / 8) * 8;
    const int nE2 = (Eb + 127) / 128, nE2p = ((nE2 + 7) / 8) * 8;

    // ---- workspace carve (256B aligned) ----
    char* p = (char*)d_ws;
    auto alloc = [&](size_t bytes) {
        char* r = p;
        p += (bytes + 255) & ~(size_t)255;
        return (void*)r;
    };
    float* x0   = (float*)alloc((size_t)N * 64 * 4);
    float* hA   = (float*)alloc((size_t)N * 64 * 4);
    float* hB   = (float*)alloc((size_t)N * 64 * 4);
    float* sbuf = (float*)alloc((size_t)2 * N * 64 * 4);   // s1 | s2
    float* cnt  = (float*)alloc((size_t)2 * N * 4);        // cnt1 | cnt2
    size_t h2aBytes = (size_t)nE1p * 128 * K2DIM * 2;      // packed, padded rows
    size_t h2bBytes = (size_t)nE2p * 128 * K2DIM * 2;
    u16*   h2a  = (u16*)alloc(h2aBytes);
    u16*   h2b  = (u16*)alloc(h2bBytes);
    u16*   Bp1  = (u16*)alloc((size_t)KERW * K2DIM * 2);
    u16*   Bp2  = (u16*)alloc((size_t)KERW * K2DIM * 2);
    float* b3p1 = (float*)alloc((size_t)KERW * 4);
    float* b3p2 = (float*)alloc((size_t)KERW * 4);
    u16*   W1   = (u16*)alloc((size_t)E * KERW * 2);
    u16*   W2   = (u16*)alloc((size_t)Eb * KERW * 2);
    (void)ws_size;

    const int* src1 = ei;       const int* dst1 = ei + E;
    const int* src2 = eib;      const int* dst2 = eib + Eb;

    // ---- precompute phase ----
    hipMemsetAsync(cnt, 0, (size_t)2 * N * 4, stream);
    hipMemsetAsync(h2a, 0, h2aBytes, stream);   // zero pad rows for clamp-free GEMM
    hipMemsetAsync(h2b, 0, h2bBytes, stream);
    {
        int tot = E + Eb;
        count_k<<<(tot + 255) / 256, 256, 0, stream>>>(dst1, E, dst2, Eb, cnt, N);
    }
    fc1_k<<<((size_t)N * 64 + 255) / 256, 256, 0, stream>>>(x, fc1w, fc1b, x0, N);

    mlp12_k<<<(E + MEB - 1) / MEB, 256, 0, stream>>>(ea, k1w1, k1b1, k1w2, k1b2, h2a, E);
    mlp12_k<<<(Eb + MEB - 1) / MEB, 256, 0, stream>>>(eab, k2w1, k2b1, k2w2, k2b2, h2b, Eb);

    prep_b_k<<<(KERW * K2DIM) / 256, 256, 0, stream>>>(k1w3, k1b3, Bp1, b3p1);
    prep_b_k<<<(KERW * K2DIM) / 256, 256, 0, stream>>>(k2w3, k2b3, Bp2, b3p2);

    w3_mfma_k<<<nE1p * 32, 256, 0, stream>>>(h2a, Bp1, b3p1, W1, E, nE1);
    w3_mfma_k<<<nE2p * 32, 256, 0, stream>>>(h2b, Bp2, b3p2, W2, Eb, nE2);

    // ---- 4 message-passing layers ----
    const float* hcur = x0;
    float* bufs[2] = { hA, hB };
    for (int l = 0; l < DEPTH; ++l) {
        float* hnext = bufs[l & 1];
        hipMemsetAsync(sbuf, 0, (size_t)2 * N * 64 * 4, stream);
        msg_k<<<(E + 3) / 4, 256, 0, stream>>>(hcur, W1, src1, dst1, sbuf, E);
        msg_k<<<(Eb + 3) / 4, 256, 0, stream>>>(hcur, W2, src2, dst2, sbuf + (size_t)N * 64, Eb);
        combine_k<<<(N + 15) / 16, 256, 0, stream>>>(hcur, sbuf, cnt, root1, root2, bias1, bias2,
                                                     x0, hnext, N);
        hcur = hnext;
    }

    // ---- head ----
    head_k<<<N, 128, 0, stream>>>(hcur, fc2w, fc2b, fc3w, fc3b, out, N);
}

// Round 8
// 307.945 us; speedup vs baseline: 2.4459x; 1.0436x over previous
//
#include <hip/hip_runtime.h>
#include <hip/hip_bf16.h>

typedef unsigned short u16;
typedef unsigned int u32;
typedef unsigned long long u64;

#define WIDTH 64
#define KERW 4096   // 64*64
#define K2DIM 128
#define DEPTH 4
#define MEB 16      // edges per mlp12 block

typedef __attribute__((ext_vector_type(8))) short short8;
typedef __attribute__((ext_vector_type(4))) float f32x4;
typedef __attribute__((ext_vector_type(4))) u32 u32x4;
typedef __attribute__((ext_vector_type(4))) u16 u16x4;

__device__ __forceinline__ u16 f2bf(float f) {
    union { float f; u32 u; } v; v.f = f;
    u32 r = v.u + 0x7FFFu + ((v.u >> 16) & 1u);
    return (u16)(r >> 16);
}
__device__ __forceinline__ float bflo(u32 u) { return __uint_as_float(u << 16); }
__device__ __forceinline__ float bfhi(u32 u) { return __uint_as_float(u & 0xFFFF0000u); }

// Stored W layout: pos o*64 + sig(i) holds W[e][i][o], sig(i) = (i&15)*4 + (i>>4).
// h2 / Bp fragment-packed: idx_u16(row,k) = (row>>4)*2048 + (k>>5)*512
//   + ((row&15) + 16*((k>>3)&3))*8 + (k&7)   => GEMM loads are 1KB wave-contiguous.

// ---------------- pre_k: count | fc1 | prep_b(set1) | prep_b(set2) ----------------
__global__ void pre_k(const int* __restrict__ dst1, int E,
                      const int* __restrict__ dst2, int Eb,
                      float* __restrict__ cnt, int N,
                      const float* __restrict__ x, const float* __restrict__ fc1w,
                      const float* __restrict__ fc1b, float* __restrict__ x0,
                      const float* __restrict__ w3a, const float* __restrict__ b3a,
                      u16* __restrict__ Bp1, float* __restrict__ b3p1,
                      const float* __restrict__ w3b, const float* __restrict__ b3b,
                      u16* __restrict__ Bp2, float* __restrict__ b3p2,
                      int nbC, int nbF) {
    int bid = blockIdx.x, t = threadIdx.x;
    if (bid < nbC) {
        int i = bid * 256 + t;
        if (i < E) atomicAdd(&cnt[dst1[i]], 1.0f);
        else if (i < E + Eb) atomicAdd(&cnt[N + dst2[i - E]], 1.0f);
        return;
    }
    bid -= nbC;
    if (bid < nbF) {
        int idx = bid * 256 + t;
        if (idx < N * WIDTH) {
            int n = idx >> 6, j = idx & 63;
            x0[idx] = fc1w[j] * x[n] + fc1b[j];
        }
        return;
    }
    bid -= nbF;
    const float* w3 = w3a; const float* b3 = b3a;
    u16* Bp = Bp1; float* b3p = b3p1;
    if (bid >= 2048) { bid -= 2048; w3 = w3b; b3 = b3b; Bp = Bp2; b3p = b3p2; }
    int idx = bid * 256 + t;   // 4096*128
    int c = idx >> 7, k = idx & 127;
    int i = c & 63, o = c >> 6;
    int pr = (i << 6) | o;
    size_t w = (size_t)(c >> 4) * 2048 + (k >> 5) * 512
             + (((c & 15) + 16 * ((k >> 3) & 3)) << 3) + (k & 7);
    Bp[w] = f2bf(w3[(size_t)pr * 128 + k]);
    if (k == 0) b3p[(o << 6) | ((i & 15) << 2) | (i >> 4)] = b3[pr];
}

// ---------------- kernel-MLP layers 1+2 (both edge sets): -> h2 packed bf16 ----------------
__global__ __launch_bounds__(256) void mlp12_k(const float* __restrict__ eaA,
                                               const float* __restrict__ w1A, const float* __restrict__ b1A,
                                               const float* __restrict__ w2A, const float* __restrict__ b2A,
                                               u16* __restrict__ h2A, int EA, int nbA,
                                               const float* __restrict__ eaB,
                                               const float* __restrict__ w1B, const float* __restrict__ b1B,
                                               const float* __restrict__ w2B, const float* __restrict__ b2B,
                                               u16* __restrict__ h2B, int EB) {
    __shared__ u16   w2b[64 * 136];   // [j][o], pad 136 for conflict-free b128 reads
    __shared__ float h1s[MEB * 65];   // [el][j], stride 65
    __shared__ float w1s[64 * 6];
    __shared__ float b1s[64];
    __shared__ float b2s[128];
    __shared__ float eas[MEB * 6];
    int bid = blockIdx.x, t = threadIdx.x;
    const float *ea, *w1, *b1, *w2, *b2; u16* h2p; int E, e0;
    if (bid < nbA) { ea = eaA; w1 = w1A; b1 = b1A; w2 = w2A; b2 = b2A; h2p = h2A; E = EA; e0 = bid * MEB; }
    else { ea = eaB; w1 = w1B; b1 = b1B; w2 = w2B; b2 = b2B; h2p = h2B; E = EB; e0 = (bid - nbA) * MEB; }
    // stage weights
    for (int i = t; i < 8192; i += 256)          // w2[o*64+j] -> w2b[j*136+o]
        w2b[(i & 63) * 136 + (i >> 6)] = f2bf(w2[i]);
    for (int i = t; i < 384; i += 256) w1s[i] = w1[i];
    if (t < 64) b1s[t] = b1[t];
    if (t < 128) b2s[t] = b2[t];
    {
        int ne = min(MEB, E - e0) * 6;
        if (t < ne) eas[t] = ea[(size_t)e0 * 6 + t];
    }
    __syncthreads();
    // phase 1: h1[el][o] for 16 edges
    for (int id = t; id < MEB * 64; id += 256) {
        int el = id >> 6, o = id & 63;
        float a = b1s[o];
        #pragma unroll
        for (int k = 0; k < 6; ++k) a += eas[el * 6 + k] * w1s[o * 6 + k];
        h1s[el * 65 + o] = fmaxf(a, 0.f);
    }
    __syncthreads();
    // phase 2: h2[el][og..og+7] per thread
    int el = t >> 4, og = (t & 15) * 8;
    int e = e0 + el;
    float acc[8];
    #pragma unroll
    for (int c = 0; c < 8; ++c) acc[c] = b2s[og + c];
    const float* h1r = &h1s[el * 65];
    #pragma unroll 8
    for (int j = 0; j < 64; ++j) {
        float hj = h1r[j];
        uint4 v = *(const uint4*)&w2b[j * 136 + og];
        acc[0] += bflo(v.x) * hj; acc[1] += bfhi(v.x) * hj;
        acc[2] += bflo(v.y) * hj; acc[3] += bfhi(v.y) * hj;
        acc[4] += bflo(v.z) * hj; acc[5] += bfhi(v.z) * hj;
        acc[6] += bflo(v.w) * hj; acc[7] += bfhi(v.w) * hj;
    }
    if (e < E) {
        size_t idx = (size_t)(e >> 4) * 2048 + (og >> 5) * 512
                   + (((e & 15) + 16 * ((og >> 3) & 3)) << 3);
        ushort4 p0, p1;
        p0.x = f2bf(fmaxf(acc[0], 0.f)); p0.y = f2bf(fmaxf(acc[1], 0.f));
        p0.z = f2bf(fmaxf(acc[2], 0.f)); p0.w = f2bf(fmaxf(acc[3], 0.f));
        p1.x = f2bf(fmaxf(acc[4], 0.f)); p1.y = f2bf(fmaxf(acc[5], 0.f));
        p1.z = f2bf(fmaxf(acc[6], 0.f)); p1.w = f2bf(fmaxf(acc[7], 0.f));
        *(ushort4*)(h2p + idx)     = p0;
        *(ushort4*)(h2p + idx + 4) = p1;
    }
}

// ---------------- big GEMM via MFMA, LDS-free, packed operands, both sets ----------------
__global__ __launch_bounds__(256, 4) void w3_mfma_k(const u16* __restrict__ h2A,
                                                    const u16* __restrict__ BpA,
                                                    const float* __restrict__ b3pA,
                                                    u16* __restrict__ WtA, int EA, int nEA, int g1,
                                                    const u16* __restrict__ h2B,
                                                    const u16* __restrict__ BpB,
                                                    const float* __restrict__ b3pB,
                                                    u16* __restrict__ WtB, int EB, int nEB) {
    int p = blockIdx.x;
    const u16 *h2p, *Bp; const float* b3p; u16* Wt; int E, nE;
    if (p < g1) { h2p = h2A; Bp = BpA; b3p = b3pA; Wt = WtA; E = EA; nE = nEA; }
    else { p -= g1; h2p = h2B; Bp = BpB; b3p = b3pB; Wt = WtB; E = EB; nE = nEB; }
    int xcd = p & 7, j = p >> 3;
    int t = (j >> 5) * 8 + xcd;          // e-tile (grid padded to x8 tiles, zero-padded data)
    if (t >= nE) return;
    int eb = t << 7, cb = (j & 31) << 7;

    int lane = threadIdx.x & 63, wv = threadIdx.x >> 6;
    int wr = (wv >> 1) << 6, wc = (wv & 1) << 6;
    int lr = lane & 15, lg = lane >> 4;

    const u16* abase = h2p + (size_t)((eb + wr) >> 4) * 2048 + lane * 8;
    const u16* bbase = Bp  + (size_t)((cb + wc) >> 4) * 2048 + lane * 8;

    f32x4 acc[4][4] = {};
    #pragma unroll
    for (int kk = 0; kk < 4; ++kk) {
        short8 af[4], bf[4];
        #pragma unroll
        for (int m = 0; m < 4; ++m) af[m] = *(const short8*)(abase + m * 2048 + kk * 512);
        #pragma unroll
        for (int n = 0; n < 4; ++n) bf[n] = *(const short8*)(bbase + n * 2048 + kk * 512);
        #pragma unroll
        for (int m = 0; m < 4; ++m)
            #pragma unroll
            for (int n = 0; n < 4; ++n)
                acc[m][n] = __builtin_amdgcn_mfma_f32_16x16x32_bf16(af[m], bf[n], acc[m][n], 0, 0, 0);
    }

    float4 bb4 = *(const float4*)(b3p + cb + wc + lr * 4);

    #pragma unroll
    for (int m = 0; m < 4; ++m) {
        #pragma unroll
        for (int r4 = 0; r4 < 4; ++r4) {
            int eg = eb + wr + m * 16 + lg * 4 + r4;
            if (eg < E) {
                u16x4 pk;
                pk[0] = f2bf(acc[m][0][r4] + bb4.x);
                pk[1] = f2bf(acc[m][1][r4] + bb4.y);
                pk[2] = f2bf(acc[m][2][r4] + bb4.z);
                pk[3] = f2bf(acc[m][3][r4] + bb4.w);
                __builtin_nontemporal_store(pk, (u16x4*)(Wt + (size_t)eg * KERW + cb + wc + lr * 4));
            }
        }
    }
}

// ---------------- message + scatter-add (both edge sets), nt W reads ----------------
__global__ __launch_bounds__(256) void msg_k(const float* __restrict__ h,
                                             const u16* __restrict__ WtA,
                                             const int* __restrict__ srcA, const int* __restrict__ dstA,
                                             float* __restrict__ sA, int EA, int nbA,
                                             const u16* __restrict__ WtB,
                                             const int* __restrict__ srcB, const int* __restrict__ dstB,
                                             float* __restrict__ sB, int EB) {
    __shared__ float hs[4][64];
    int bid = blockIdx.x;
    int w = threadIdx.x >> 6, l = threadIdx.x & 63;
    const u16* Wt; const int *src, *dst; float* s; int E, e;
    if (bid < nbA) { Wt = WtA; src = srcA; dst = dstA; s = sA; E = EA; e = bid * 4 + w; }
    else { Wt = WtB; src = srcB; dst = dstB; s = sB; E = EB; e = (bid - nbA) * 4 + w; }
    bool valid = e < E;
    int ec = valid ? e : 0;
    int sv = src[ec];
    hs[w][((l & 15) << 2) | (l >> 4)] = h[(size_t)sv * 64 + l];   // sig-permuted staging
    __syncthreads();
    float4 h0 = *(const float4*)&hs[w][(l & 7) * 8];
    float4 h1 = *(const float4*)&hs[w][(l & 7) * 8 + 4];
    const char* base = (const char*)(Wt + (size_t)ec * KERW) + l * 16;
    float acc[8];
    #pragma unroll
    for (int jj = 0; jj < 8; ++jj) {
        u32x4 v = __builtin_nontemporal_load((const u32x4*)(base + jj * 1024));
        float a;
        a  = bflo(v[0]) * h0.x; a += bfhi(v[0]) * h0.y;
        a += bflo(v[1]) * h0.z; a += bfhi(v[1]) * h0.w;
        a += bflo(v[2]) * h1.x; a += bfhi(v[2]) * h1.y;
        a += bflo(v[3]) * h1.z; a += bfhi(v[3]) * h1.w;
        acc[jj] = a;
    }
    #pragma unroll
    for (int jj = 0; jj < 8; ++jj) {
        acc[jj] += __shfl_xor(acc[jj], 1, 64);
        acc[jj] += __shfl_xor(acc[jj], 2, 64);
        acc[jj] += __shfl_xor(acc[jj], 4, 64);
    }
    int c = l & 7;
    float val = acc[0];
    #pragma unroll
    for (int jj = 1; jj < 8; ++jj) val = (c == jj) ? acc[jj] : val;   // static idx
    if (valid) atomicAdd(&s[(size_t)dst[ec] * 64 + ((c << 3) | (l >> 3))], val);
}

// ---------------- combine: mean + h@(root1+root2) + biases, relu, +x0; re-zero s ----------------
__global__ __launch_bounds__(256) void combine_k(const float* __restrict__ h,
                                                 float* __restrict__ s,         // [2][N][64]
                                                 const float* __restrict__ cnt, // [2][N]
                                                 const float* __restrict__ root1, const float* __restrict__ root2,
                                                 const float* __restrict__ bias1, const float* __restrict__ bias2,
                                                 const float* __restrict__ x0, float* __restrict__ hout, int N) {
    __shared__ float rs[64][64];
    __shared__ float hr[4][64];
    int t = threadIdx.x;
    for (int j = t; j < 4096; j += 256) rs[j >> 6][j & 63] = root1[j] + root2[j];
    int w = t >> 6, o = t & 63;
    float bsum = bias1[o] + bias2[o];
    __syncthreads();
    #pragma unroll
    for (int g = 0; g < 4; ++g) {
        int n = blockIdx.x * 16 + g * 4 + w;
        bool valid = n < N;
        int nc = valid ? n : 0;
        hr[w][o] = h[(size_t)nc * 64 + o];   // wave-private region, lockstep
        float inv1 = 1.0f / fmaxf(cnt[nc], 1.0f);
        float inv2 = 1.0f / fmaxf(cnt[N + nc], 1.0f);
        float acc = s[(size_t)nc * 64 + o] * inv1
                  + s[(size_t)(N + nc) * 64 + o] * inv2
                  + bsum;
        if (valid) {   // re-zero for next layer (each (n,o) owned by exactly one thread)
            s[(size_t)nc * 64 + o] = 0.f;
            s[(size_t)(N + nc) * 64 + o] = 0.f;
        }
        #pragma unroll 8
        for (int i = 0; i < 64; ++i) acc += hr[w][i] * rs[i][o];
        if (valid) hout[(size_t)n * 64 + o] = fmaxf(acc, 0.f) + x0[(size_t)n * 64 + o];
    }
}

// ---------------- head: out[n] = fc3( relu(fc2(h[n])) ) ----------------
__global__ __launch_bounds__(128) void head_k(const float* __restrict__ h,
                                              const float* __restrict__ fc2w, const float* __restrict__ fc2b,
                                              const float* __restrict__ fc3w, const float* __restrict__ fc3b,
                                              float* __restrict__ out, int N) {
    __shared__ float hr[64];
    __shared__ float red[128];
    int n = blockIdx.x, t = threadIdx.x;
    if (t < 64) hr[t] = h[(size_t)n * 64 + t];
    __syncthreads();
    float a = fc2b[t];
    #pragma unroll 8
    for (int i = 0; i < 64; ++i) a += hr[i] * fc2w[t * 64 + i];
    red[t] = fmaxf(a, 0.f) * fc3w[t];
    __syncthreads();
    if (t < 64) {
        float v = red[t] + red[t + 64];
        for (int off = 32; off; off >>= 1) v += __shfl_down(v, off);
        if (t == 0) out[n] = v + fc3b[0];
    }
}

extern "C" void kernel_launch(void* const* d_in, const int* in_sizes, int n_in,
                              void* d_out, int out_size, void* d_ws, size_t ws_size,
                              hipStream_t stream) {
    const float* x    = (const float*)d_in[0];
    const int*   ei   = (const int*)d_in[1];
    const float* ea   = (const float*)d_in[2];
    const int*   eib  = (const int*)d_in[3];
    const float* eab  = (const float*)d_in[4];
    const float* fc1w = (const float*)d_in[5];
    const float* fc1b = (const float*)d_in[6];
    const float* fc2w = (const float*)d_in[7];
    const float* fc2b = (const float*)d_in[8];
    const float* fc3w = (const float*)d_in[9];
    const float* fc3b = (const float*)d_in[10];
    const float* k1w1 = (const float*)d_in[11];
    const float* k1b1 = (const float*)d_in[12];
    const float* k1w2 = (const float*)d_in[13];
    const float* k1b2 = (const float*)d_in[14];
    const float* k1w3 = (const float*)d_in[15];
    const float* k1b3 = (const float*)d_in[16];
    const float* root1 = (const float*)d_in[17];
    const float* bias1 = (const float*)d_in[18];
    const float* k2w1 = (const float*)d_in[19];
    const float* k2b1 = (const float*)d_in[20];
    const float* k2w2 = (const float*)d_in[21];
    const float* k2b2 = (const float*)d_in[22];
    const float* k2w3 = (const float*)d_in[23];
    const float* k2b3 = (const float*)d_in[24];
    const float* root2 = (const float*)d_in[25];
    const float* bias2 = (const float*)d_in[26];
    float* out = (float*)d_out;

    const int N  = in_sizes[0];
    const int E  = in_sizes[2] / 6;
    const int Eb = in_sizes[4] / 6;

    const int nE1 = (E + 127) / 128,  nE1p = ((nE1 + 7) / 8) * 8;
    const int nE2 = (Eb + 127) / 128, nE2p = ((nE2 + 7) / 8) * 8;

    // ---- workspace carve (256B aligned) ----
    char* p = (char*)d_ws;
    auto alloc = [&](size_t bytes) {
        char* r = p;
        p += (bytes + 255) & ~(size_t)255;
        return (void*)r;
    };
    float* x0   = (float*)alloc((size_t)N * 64 * 4);
    float* hA   = (float*)alloc((size_t)N * 64 * 4);
    float* hB   = (float*)alloc((size_t)N * 64 * 4);
    float* sbuf = (float*)alloc((size_t)2 * N * 64 * 4);   // s1 | s2
    float* cnt  = (float*)alloc((size_t)2 * N * 4);        // cnt1 | cnt2
    char*  zero0 = (char*)sbuf;
    size_t zero0Bytes = (size_t)((char*)cnt - (char*)sbuf) + (size_t)2 * N * 4;
    size_t h2aBytes = (size_t)nE1p * 128 * K2DIM * 2;      // packed, padded rows
    size_t h2bBytes = (size_t)nE2p * 128 * K2DIM * 2;
    u16*   h2a  = (u16*)alloc(h2aBytes);
    u16*   h2b  = (u16*)alloc(h2bBytes);
    size_t zero1Bytes = (size_t)((char*)h2b - (char*)h2a) + h2bBytes;
    u16*   Bp1  = (u16*)alloc((size_t)KERW * K2DIM * 2);
    u16*   Bp2  = (u16*)alloc((size_t)KERW * K2DIM * 2);
    float* b3p1 = (float*)alloc((size_t)KERW * 4);
    float* b3p2 = (float*)alloc((size_t)KERW * 4);
    u16*   W1   = (u16*)alloc((size_t)E * KERW * 2);
    u16*   W2   = (u16*)alloc((size_t)Eb * KERW * 2);
    (void)ws_size;

    const int* src1 = ei;       const int* dst1 = ei + E;
    const int* src2 = eib;      const int* dst2 = eib + Eb;

    // ---- precompute phase ----
    hipMemsetAsync(zero0, 0, zero0Bytes, stream);           // sbuf + cnt
    hipMemsetAsync(h2a, 0, zero1Bytes, stream);             // h2a + h2b (pad rows -> zeros)

    {
        int nbA = (E + MEB - 1) / MEB, nbB = (Eb + MEB - 1) / MEB;
        mlp12_k<<<nbA + nbB, 256, 0, stream>>>(ea, k1w1, k1b1, k1w2, k1b2, h2a, E, nbA,
                                               eab, k2w1, k2b1, k2w2, k2b2, h2b, Eb);
    }
    {
        int nbC = (E + Eb + 255) / 256;
        int nbF = (N * WIDTH + 255) / 256;
        pre_k<<<nbC + nbF + 4096, 256, 0, stream>>>(dst1, E, dst2, Eb, cnt, N,
                                                    x, fc1w, fc1b, x0,
                                                    k1w3, k1b3, Bp1, b3p1,
                                                    k2w3, k2b3, Bp2, b3p2,
                                                    nbC, nbF);
    }
    {
        int g1 = nE1p * 32, g2 = nE2p * 32;
        w3_mfma_k<<<g1 + g2, 256, 0, stream>>>(h2a, Bp1, b3p1, W1, E, nE1, g1,
                                               h2b, Bp2, b3p2, W2, Eb, nE2);
    }

    // ---- 4 message-passing layers ----
    const float* hcur = x0;
    float* bufs[2] = { hA, hB };
    int nbM1 = (E + 3) / 4, nbM2 = (Eb + 3) / 4;
    for (int l = 0; l < DEPTH; ++l) {
        float* hnext = bufs[l & 1];
        msg_k<<<nbM1 + nbM2, 256, 0, stream>>>(hcur, W1, src1, dst1, sbuf, E, nbM1,
                                               W2, src2, dst2, sbuf + (size_t)N * 64, Eb);
        combine_k<<<(N + 15) / 16, 256, 0, stream>>>(hcur, sbuf, cnt, root1, root2, bias1, bias2,
                                                     x0, hnext, N);
        hcur = hnext;
    }

    // ---- head ----
    head_k<<<N, 128, 0, stream>>>(hcur, fc2w, fc2b, fc3w, fc3b, out, N);
}